// Round 2
// 162.413 us; speedup vs baseline: 1.1079x; 1.1079x over previous
//
#include <hip/hip_runtime.h>

typedef float f4v __attribute__((ext_vector_type(4)));
typedef _Float16 h2v __attribute__((ext_vector_type(2)));
typedef _Float16 h4v __attribute__((ext_vector_type(4)));
typedef _Float16 h8v __attribute__((ext_vector_type(8)));
typedef __fp16 g4 __attribute__((ext_vector_type(4)));
typedef __fp16 g8 __attribute__((ext_vector_type(8)));
typedef unsigned short u16;
typedef unsigned int u32;

// B=2, T=192, C=512, H=8, HS=64, ORDER=3; scale = 1/sqrt(64) = 0.125
#define SPLIT 8
#define ESC 0.18033688011112042f  // 0.125 * log2(e), folded into Q at proj

__device__ __forceinline__ h2v pkh(float lo, float hi) {
  return __builtin_bit_cast(h2v, __builtin_amdgcn_cvt_pkrtz(lo, hi));
}
__device__ __forceinline__ f4v mfma_k32(h8v a, h8v b, f4v c) {
  return __builtin_amdgcn_mfma_f32_16x16x32_f16(
      __builtin_bit_cast(g8, a), __builtin_bit_cast(g8, b), c, 0, 0, 0);
}
__device__ __forceinline__ f4v mfma_k16(h4v a, h4v b, f4v c) {
  return __builtin_amdgcn_mfma_f32_16x16x16f16(
      __builtin_bit_cast(g4, a), __builtin_bit_cast(g4, b), c, 0, 0, 0);
}

// ---------------- projection kernel ----------------
// grid = 5 slots * 16 bh * 6 t-tiles = 480 blocks, 256 threads.
// Tile 32(t) x 64(d), K=512, register-dbuf staging.
// Outputs: Q0h/K1h/K2b/V2b as f16 (Q pre-scaled by ESC), V1f as f32
// (V1 multiplies outside MFMA -> keep full precision there).
__global__ __launch_bounds__(256) void proj_kernel(
    const float* __restrict__ x0, const float* __restrict__ x1,
    const float* __restrict__ x2,
    const float* __restrict__ qw, const float* __restrict__ qb,
    const float* __restrict__ kw, const float* __restrict__ kb,
    const float* __restrict__ vw, const float* __restrict__ vb,
    u16* __restrict__ Q0h, u16* __restrict__ K1h, float* __restrict__ V1f,
    u16* __restrict__ K2b, u16* __restrict__ V2b) {
  __shared__ float xs[32][36];   // [c][m]
  __shared__ float wsh[32][68];  // [c][n]

  int bx = blockIdx.x;
  int slot = bx / 96;
  int rem = bx - slot * 96;
  int bh = rem / 6;
  int tt = rem - bh * 6;
  int b = bh >> 3, h = bh & 7;
  int t0 = tt * 32;

  const float* x; const float* w; const float* bias; int o;
  float* outf = nullptr; u16* outb = nullptr;
  switch (slot) {
    case 0: x = x0; w = qw; bias = qb; o = 0; outb = Q0h; break;
    case 1: x = x1; w = kw; bias = kb; o = 1; outb = K1h; break;
    case 2: x = x2; w = kw; bias = kb; o = 2; outb = K2b; break;
    case 3: x = x1; w = vw; bias = vb; o = 1; outf = V1f; break;
    default: x = x2; w = vw; bias = vb; o = 2; outb = V2b; break;
  }
  x += b * 192 * 512;
  w += (h * 3 + o) * 64 * 512;
  bias += (h * 3 + o) * 64;

  int tid = threadIdx.x;
  int m2 = tid >> 4, nq = tid & 15;
  int mA = tid >> 3, clA = (tid & 7) * 4;      // A-stage coords
  int nB0 = tid >> 3, nB1 = (256 + tid) >> 3;  // B-stage coords (2 rows)
  float acc[2][4] = {};

  float4 pX, pW0, pW1;  // prefetch registers
  pX = *(const float4*)(x + (t0 + mA) * 512 + clA);
  pW0 = *(const float4*)(w + nB0 * 512 + clA);
  pW1 = *(const float4*)(w + nB1 * 512 + clA);

  for (int kc = 0; kc < 16; ++kc) {
    xs[clA][mA] = pX.x; xs[clA + 1][mA] = pX.y;
    xs[clA + 2][mA] = pX.z; xs[clA + 3][mA] = pX.w;
    wsh[clA][nB0] = pW0.x; wsh[clA + 1][nB0] = pW0.y;
    wsh[clA + 2][nB0] = pW0.z; wsh[clA + 3][nB0] = pW0.w;
    wsh[clA][nB1] = pW1.x; wsh[clA + 1][nB1] = pW1.y;
    wsh[clA + 2][nB1] = pW1.z; wsh[clA + 3][nB1] = pW1.w;
    __syncthreads();
    if (kc < 15) {  // prefetch next tile; latency hidden by compute below
      int cb0 = (kc + 1) * 32;
      pX = *(const float4*)(x + (t0 + mA) * 512 + cb0 + clA);
      pW0 = *(const float4*)(w + nB0 * 512 + cb0 + clA);
      pW1 = *(const float4*)(w + nB1 * 512 + cb0 + clA);
    }
#pragma unroll
    for (int c = 0; c < 32; ++c) {
      float2 av = *(const float2*)&xs[c][m2 * 2];
      float4 bv = *(const float4*)&wsh[c][nq * 4];
      acc[0][0] += av.x * bv.x; acc[0][1] += av.x * bv.y;
      acc[0][2] += av.x * bv.z; acc[0][3] += av.x * bv.w;
      acc[1][0] += av.y * bv.x; acc[1][1] += av.y * bv.y;
      acc[1][2] += av.y * bv.z; acc[1][3] += av.y * bv.w;
    }
    __syncthreads();
  }

  float4 bias4 = *(const float4*)(bias + nq * 4);
#pragma unroll
  for (int i = 0; i < 2; ++i) {
    int t = t0 + m2 * 2 + i;
    long base = ((long)(bh * 192 + t)) * 64 + nq * 4;
    float o0 = acc[i][0] + bias4.x;
    float o1 = acc[i][1] + bias4.y;
    float o2 = acc[i][2] + bias4.z;
    float o3 = acc[i][3] + bias4.w;
    if (slot == 0) {  // fold attention scale+log2e into Q
      o0 *= ESC; o1 *= ESC; o2 *= ESC; o3 *= ESC;
    }
    if (outf) {
      float4 st = {o0, o1, o2, o3};
      *(float4*)(outf + base) = st;
    } else {
      h2v a = pkh(o0, o1), c2 = pkh(o2, o3);
      uint2 st = {__builtin_bit_cast(u32, a), __builtin_bit_cast(u32, c2)};
      *(uint2*)(outb + base) = st;
    }
  }
}

// ---------------- attention kernel ----------------
// grid = SPLIT*16*12 = 1536 blocks, 256 threads (4 waves), LDS = 25600 B.
//
// Operand-swapped scores: S^T = mfma(A=K2, B=Q*K1) puts the output with
// i in lane&15 and k in (quad, reg) -- which is EXACTLY the A-fragment
// layout for the PV matmul.  So P = exp2(S) never touches LDS: convert
// in-register with cvt_pkrtz and feed the PV mfma directly.  No barriers
// in the main loop; waves are independent (each owns a 48-k slice, all d).
// Per-wave partial O (over its k slice) is reduced across waves in a tiny
// LDS epilogue.  LDS is only used for the V2^T prologue stage + epilogue.
__global__ __launch_bounds__(256, 4) void attn_kernel(
    const u16* __restrict__ Q0h, const u16* __restrict__ K1h,
    const float* __restrict__ V1f, const u16* __restrict__ K2b,
    const u16* __restrict__ V2b, float* __restrict__ Op,
    float* __restrict__ lp) {
  __shared__ __align__(16) char smem[25600];
  int bx = blockIdx.x;
  int sp = bx / 192;
  int rem = bx - sp * 192;
  int bh = rem / 12;
  int itile = rem - bh * 12;
  int i0 = itile * 16;
  int js = sp * 24;
  int tid = threadIdx.x;
  int wave = tid >> 6;
  int lane = tid & 63;
  int l15 = lane & 15;
  int quad = lane >> 4;

  // ---- prologue: stage V2^T [64 d][200 pad] u16 (natural k order)
  u16* V2T = (u16*)smem;
  {
    const u32* vsrc = (const u32*)V2b + bh * 6144;
#pragma unroll
    for (int r = 0; r < 24; ++r) {
      int idx = r * 256 + tid;
      int k = idx >> 5, d2 = idx & 31;
      u32 v = vsrc[idx];
      V2T[(d2 * 2) * 200 + k] = (u16)v;
      V2T[(d2 * 2 + 1) * 200 + k] = (u16)(v >> 16);
    }
  }
  // K2 A-fragments straight from global (rows k = w*48+nt*16+l15, kdim d)
  h8v k2f[3][2];
#pragma unroll
  for (int nt = 0; nt < 3; ++nt)
#pragma unroll
    for (int ks = 0; ks < 2; ++ks)
      k2f[nt][ks] = *(const h8v*)(K2b +
          (bh * 192 + wave * 48 + nt * 16 + l15) * 64 + ks * 32 + quad * 8);
  // Q B-fragments (kdim d = quad*8+idx (+32), col i = l15), pre-scaled ESC
  const u16* qq = Q0h + (bh * 192 + i0 + l15) * 64 + quad * 8;
  h8v qh0 = *(const h8v*)qq;
  h8v qh1 = *(const h8v*)(qq + 32);
  __syncthreads();
  // V2 B-fragments for PV: grp0 k = w48+{quad*4+0..3, 16+quad*4+0..3},
  // grp1 k = w48+32+quad*4+0..3; col d = dt*16+l15.  Same k-order as pa.
  h8v v2g0[4]; h4v v2g1[4];
#pragma unroll
  for (int dt = 0; dt < 4; ++dt) {
    const char* p = smem + (dt * 16 + l15) * 400 + wave * 96 + quad * 8;
    union { h8v v; h4v h[2]; } u;
    u.h[0] = *(const h4v*)p;
    u.h[1] = *(const h4v*)(p + 32);
    v2g0[dt] = u.v;
    v2g1[dt] = *(const h4v*)(p + 64);
  }
  __syncthreads();  // all frags in regs; smem reusable by epilogue

  f4v Oacc[4] = {};
  float lsum = 0.f;
  const u16* krow = K1h + (bh * 192 + js) * 64;
  const float* vrow = V1f + (bh * 192 + js) * 64;
  const f4v z = {0.f, 0.f, 0.f, 0.f};

#pragma unroll 1
  for (int j = 0; j < 24; ++j) {
    // B-frag of S^T: Q~[i,d]*K1[j,d] via packed f16 mul
    h8v c0 = *(const h8v*)(krow + j * 64 + quad * 8);
    h8v c1 = *(const h8v*)(krow + j * 64 + 32 + quad * 8);
    h8v B0 = qh0 * c0, B1 = qh1 * c1;
    // S^T[k=w48+nt*16+quad*4+r][i=l15], sum over d=0..63
    f4v s0 = mfma_k32(k2f[0][0], B0, z);
    f4v s1 = mfma_k32(k2f[1][0], B0, z);
    f4v s2 = mfma_k32(k2f[2][0], B0, z);
    s0 = mfma_k32(k2f[0][1], B1, s0);
    s1 = mfma_k32(k2f[1][1], B1, s1);
    s2 = mfma_k32(k2f[2][1], B1, s2);
    float p[12];
#pragma unroll
    for (int r = 0; r < 4; ++r) {
      p[r] = __builtin_amdgcn_exp2f(s0[r]);
      p[4 + r] = __builtin_amdgcn_exp2f(s1[r]);
      p[8 + r] = __builtin_amdgcn_exp2f(s2[r]);
    }
    lsum += (((p[0] + p[1]) + (p[2] + p[3])) + ((p[4] + p[5]) + (p[6] + p[7]))) +
            ((p[8] + p[9]) + (p[10] + p[11]));
    // P already in A-fragment layout: row i=l15, k in (quad, idx)
    union { h8v v; h2v h[4]; } pa0;
    pa0.h[0] = pkh(p[0], p[1]);  pa0.h[1] = pkh(p[2], p[3]);
    pa0.h[2] = pkh(p[4], p[5]);  pa0.h[3] = pkh(p[6], p[7]);
    union { h4v v; h2v h[2]; } pa1;
    pa1.h[0] = pkh(p[8], p[9]);  pa1.h[1] = pkh(p[10], p[11]);
    float v1r0 = vrow[j * 64 + l15];
    float v1r1 = vrow[j * 64 + 16 + l15];
    float v1r2 = vrow[j * 64 + 32 + l15];
    float v1r3 = vrow[j * 64 + 48 + l15];
    // W_j[i,d] over this wave's 48 k, then O += V1[j,d]*W_j
#pragma unroll
    for (int dt = 0; dt < 4; ++dt) {
      f4v w = mfma_k32(pa0.v, v2g0[dt], z);
      w = mfma_k16(pa1.v, v2g1[dt], w);
      float v1x = dt == 0 ? v1r0 : dt == 1 ? v1r1 : dt == 2 ? v1r2 : v1r3;
      Oacc[dt][0] = fmaf(v1x, w[0], Oacc[dt][0]);
      Oacc[dt][1] = fmaf(v1x, w[1], Oacc[dt][1]);
      Oacc[dt][2] = fmaf(v1x, w[2], Oacc[dt][2]);
      Oacc[dt][3] = fmaf(v1x, w[3], Oacc[dt][3]);
    }
  }

  // ---- epilogue: cross-wave k-slice reduction of O and l
  __syncthreads();  // all waves done; smem free
  float* ored = (float*)smem;            // 4 waves x [16 i][64 d] f32
  float* lred = (float*)(smem + 16384);  // 64 f32
  float* ow = ored + wave * 1024;
#pragma unroll
  for (int dt = 0; dt < 4; ++dt)
#pragma unroll
    for (int r = 0; r < 4; ++r)
      ow[(quad * 4 + r) * 64 + dt * 16 + l15] = Oacc[dt][r];
  lsum += __shfl_xor(lsum, 16);
  lsum += __shfl_xor(lsum, 32);
  if (quad == 0) lred[wave * 16 + l15] = lsum;
  __syncthreads();
  f4v s = *(const f4v*)(ored + tid * 4);
  s += *(const f4v*)(ored + 1024 + tid * 4);
  s += *(const f4v*)(ored + 2048 + tid * 4);
  s += *(const f4v*)(ored + 3072 + tid * 4);
  *(f4v*)(Op + ((long)(sp * 16 + bh) * 192 + i0) * 64 + tid * 4) = s;
  if (tid < 16)
    lp[(sp * 16 + bh) * 192 + i0 + tid] =
        lred[tid] + lred[16 + tid] + lred[32 + tid] + lred[48 + tid];
}

// ---------------- output projection (split-combine + 1/l fused) ----------
// grid = 24 mt(16) * 8 nt(64) = 192 blocks, register-dbuf staging.
__global__ __launch_bounds__(256) void outproj_kernel(
    const float* __restrict__ Op, const float* __restrict__ lp,
    const float* __restrict__ cw, const float* __restrict__ cb,
    float* __restrict__ out) {
  __shared__ float xs[32][20];   // [c][m]
  __shared__ float wsh[32][68];  // [c][n]
  __shared__ float linv[8][16];  // [h][m]
  int bx = blockIdx.x;
  int mt = bx >> 3, nt = bx & 7;
  int m0 = mt * 16;
  int b = m0 / 192;
  int t0 = m0 - b * 192;
  int n0 = nt * 64;
  int tid = threadIdx.x;

  if (tid < 128) {
    int h = tid >> 4, ml = tid & 15;
    float s = 0.f;
#pragma unroll
    for (int sp = 0; sp < SPLIT; ++sp)
      s += lp[(sp * 16 + b * 8 + h) * 192 + t0 + ml];
    linv[h][ml] = 1.0f / s;
  }

  int mA = tid >> 3, clA = (tid & 7) * 4;  // A-stage (tid<128 only)
  int nB0 = tid >> 3, nB1 = (256 + tid) >> 3;
  int m = tid >> 4, nq = tid & 15;
  float acc[4] = {};

  float4 pA[SPLIT];
  float4 pW0, pW1;
  {  // prefetch kc = 0 (h=0, d0=0)
    if (tid < 128) {
#pragma unroll
      for (int sp = 0; sp < SPLIT; ++sp)
        pA[sp] = *(const float4*)(
            Op + (long)((sp * 16 + b * 8) * 192 + t0 + mA) * 64 + clA);
    }
    pW0 = *(const float4*)(cw + (long)(n0 + nB0) * 512 + clA);
    pW1 = *(const float4*)(cw + (long)(n0 + nB1) * 512 + clA);
  }
  __syncthreads();  // linv ready

  for (int kc = 0; kc < 16; ++kc) {
    int h = kc >> 1;
    if (tid < 128) {  // combine SPLIT partials, scale 1/l, store [c][m]
      float4 s = pA[0];
#pragma unroll
      for (int sp = 1; sp < SPLIT; ++sp) {
        s.x += pA[sp].x; s.y += pA[sp].y; s.z += pA[sp].z; s.w += pA[sp].w;
      }
      float li = linv[h][mA];
      xs[clA][mA] = s.x * li; xs[clA + 1][mA] = s.y * li;
      xs[clA + 2][mA] = s.z * li; xs[clA + 3][mA] = s.w * li;
    }
    wsh[clA][nB0] = pW0.x; wsh[clA + 1][nB0] = pW0.y;
    wsh[clA + 2][nB0] = pW0.z; wsh[clA + 3][nB0] = pW0.w;
    wsh[clA][nB1] = pW1.x; wsh[clA + 1][nB1] = pW1.y;
    wsh[clA + 2][nB1] = pW1.z; wsh[clA + 3][nB1] = pW1.w;
    __syncthreads();
    if (kc < 15) {  // prefetch next kc during compute
      int h2 = (kc + 1) >> 1, d2 = ((kc + 1) & 1) * 32;
      if (tid < 128) {
#pragma unroll
        for (int sp = 0; sp < SPLIT; ++sp)
          pA[sp] = *(const float4*)(
              Op + (long)((sp * 16 + b * 8 + h2) * 192 + t0 + mA) * 64 + d2 +
              clA);
      }
      pW0 = *(const float4*)(cw + (long)(n0 + nB0) * 512 + h2 * 64 + d2 + clA);
      pW1 = *(const float4*)(cw + (long)(n0 + nB1) * 512 + h2 * 64 + d2 + clA);
    }
#pragma unroll
    for (int c = 0; c < 32; ++c) {
      float a = xs[c][m];
      float4 bv = *(const float4*)&wsh[c][nq * 4];
      acc[0] += a * bv.x; acc[1] += a * bv.y;
      acc[2] += a * bv.z; acc[3] += a * bv.w;
    }
    __syncthreads();
  }

  float4 bias = *(const float4*)(cb + n0 + nq * 4);
  float4 st;
  st.x = acc[0] + bias.x;
  st.y = acc[1] + bias.y;
  st.z = acc[2] + bias.z;
  st.w = acc[3] + bias.w;
  *(float4*)(out + (long)(b * 192 + t0 + m) * 512 + n0 + nq * 4) = st;
}

extern "C" void kernel_launch(void* const* d_in, const int* in_sizes, int n_in,
                              void* d_out, int out_size, void* d_ws, size_t ws_size,
                              hipStream_t stream) {
  const float* x0 = (const float*)d_in[0];
  const float* x1 = (const float*)d_in[1];
  const float* x2 = (const float*)d_in[2];
  const float* qw = (const float*)d_in[3];
  const float* qb = (const float*)d_in[4];
  const float* kw = (const float*)d_in[5];
  const float* kb = (const float*)d_in[6];
  const float* vw = (const float*)d_in[7];
  const float* vb = (const float*)d_in[8];
  const float* cw = (const float*)d_in[9];
  const float* cb = (const float*)d_in[10];
  float* out = (float*)d_out;

  // workspace carve
  char* ws = (char*)d_ws;
  u16* Q0h = (u16*)(ws + 0);            // 16*192*64 f16 (pre-scaled by ESC)
  u16* K1h = (u16*)(ws + 393216);       // 16*192*64 f16
  float* V1f = (float*)(ws + 786432);   // 16*192*64 f32
  u16* K2b = (u16*)(ws + 1572864);      // 16*192*64 f16
  u16* V2b = (u16*)(ws + 1966080);      // 16*192*64 f16
  float* Op = (float*)(ws + 2359296);   // SPLIT*16*192*64 f32 = 6291456 B
  float* lp = (float*)(ws + 2359296 + (size_t)SPLIT * 786432);  // SPLIT*16*192 f32

  proj_kernel<<<480, 256, 0, stream>>>(x0, x1, x2, qw, qb, kw, kb, vw, vb,
                                       Q0h, K1h, V1f, K2b, V2b);
  attn_kernel<<<SPLIT * 192, 256, 0, stream>>>(Q0h, K1h, V1f, K2b, V2b,
                                               Op, lp);
  outproj_kernel<<<192, 256, 0, stream>>>(Op, lp, cw, cb, out);
}

// Round 6
// 160.865 us; speedup vs baseline: 1.1186x; 1.0096x over previous
//
#include <hip/hip_runtime.h>

typedef float f4v __attribute__((ext_vector_type(4)));
typedef _Float16 h2v __attribute__((ext_vector_type(2)));
typedef _Float16 h4v __attribute__((ext_vector_type(4)));
typedef _Float16 h8v __attribute__((ext_vector_type(8)));
typedef __fp16 g4 __attribute__((ext_vector_type(4)));
typedef __fp16 g8 __attribute__((ext_vector_type(8)));
typedef unsigned short u16;
typedef unsigned int u32;

// B=2, T=192, C=512, H=8, HS=64, ORDER=3; scale = 1/sqrt(64) = 0.125
#define SPLIT 8
#define ESC 0.18033688011112042f  // 0.125 * log2(e), folded into Q at proj

__device__ __forceinline__ h2v pkh(float lo, float hi) {
  return __builtin_bit_cast(h2v, __builtin_amdgcn_cvt_pkrtz(lo, hi));
}
__device__ __forceinline__ f4v mfma_k32(h8v a, h8v b, f4v c) {
  return __builtin_amdgcn_mfma_f32_16x16x32_f16(
      __builtin_bit_cast(g8, a), __builtin_bit_cast(g8, b), c, 0, 0, 0);
}
__device__ __forceinline__ f4v mfma_k16(h4v a, h4v b, f4v c) {
  return __builtin_amdgcn_mfma_f32_16x16x16f16(
      __builtin_bit_cast(g4, a), __builtin_bit_cast(g4, b), c, 0, 0, 0);
}

// ---------------- projection kernel ----------------
// grid = 5 slots * 16 bh * 6 t-tiles = 480 blocks, 256 threads.
// Tile 32(t) x 64(d), K=512, register-dbuf staging.
// Outputs: Q0h/K1h/K2b/V2b as f16 (Q pre-scaled by ESC), V1f as f32
// (V1 multiplies outside MFMA -> keep full precision there).
__global__ __launch_bounds__(256) void proj_kernel(
    const float* __restrict__ x0, const float* __restrict__ x1,
    const float* __restrict__ x2,
    const float* __restrict__ qw, const float* __restrict__ qb,
    const float* __restrict__ kw, const float* __restrict__ kb,
    const float* __restrict__ vw, const float* __restrict__ vb,
    u16* __restrict__ Q0h, u16* __restrict__ K1h, float* __restrict__ V1f,
    u16* __restrict__ K2b, u16* __restrict__ V2b) {
  __shared__ float xs[32][36];   // [c][m]
  __shared__ float wsh[32][68];  // [c][n]

  int bx = blockIdx.x;
  int slot = bx / 96;
  int rem = bx - slot * 96;
  int bh = rem / 6;
  int tt = rem - bh * 6;
  int b = bh >> 3, h = bh & 7;
  int t0 = tt * 32;

  const float* x; const float* w; const float* bias; int o;
  float* outf = nullptr; u16* outb = nullptr;
  switch (slot) {
    case 0: x = x0; w = qw; bias = qb; o = 0; outb = Q0h; break;
    case 1: x = x1; w = kw; bias = kb; o = 1; outb = K1h; break;
    case 2: x = x2; w = kw; bias = kb; o = 2; outb = K2b; break;
    case 3: x = x1; w = vw; bias = vb; o = 1; outf = V1f; break;
    default: x = x2; w = vw; bias = vb; o = 2; outb = V2b; break;
  }
  x += b * 192 * 512;
  w += (h * 3 + o) * 64 * 512;
  bias += (h * 3 + o) * 64;

  int tid = threadIdx.x;
  int m2 = tid >> 4, nq = tid & 15;
  int mA = tid >> 3, clA = (tid & 7) * 4;      // A-stage coords
  int nB0 = tid >> 3, nB1 = (256 + tid) >> 3;  // B-stage coords (2 rows)
  float acc[2][4] = {};

  float4 pX, pW0, pW1;  // prefetch registers
  pX = *(const float4*)(x + (t0 + mA) * 512 + clA);
  pW0 = *(const float4*)(w + nB0 * 512 + clA);
  pW1 = *(const float4*)(w + nB1 * 512 + clA);

  for (int kc = 0; kc < 16; ++kc) {
    xs[clA][mA] = pX.x; xs[clA + 1][mA] = pX.y;
    xs[clA + 2][mA] = pX.z; xs[clA + 3][mA] = pX.w;
    wsh[clA][nB0] = pW0.x; wsh[clA + 1][nB0] = pW0.y;
    wsh[clA + 2][nB0] = pW0.z; wsh[clA + 3][nB0] = pW0.w;
    wsh[clA][nB1] = pW1.x; wsh[clA + 1][nB1] = pW1.y;
    wsh[clA + 2][nB1] = pW1.z; wsh[clA + 3][nB1] = pW1.w;
    __syncthreads();
    if (kc < 15) {  // prefetch next tile; latency hidden by compute below
      int cb0 = (kc + 1) * 32;
      pX = *(const float4*)(x + (t0 + mA) * 512 + cb0 + clA);
      pW0 = *(const float4*)(w + nB0 * 512 + cb0 + clA);
      pW1 = *(const float4*)(w + nB1 * 512 + cb0 + clA);
    }
#pragma unroll
    for (int c = 0; c < 32; ++c) {
      float2 av = *(const float2*)&xs[c][m2 * 2];
      float4 bv = *(const float4*)&wsh[c][nq * 4];
      acc[0][0] += av.x * bv.x; acc[0][1] += av.x * bv.y;
      acc[0][2] += av.x * bv.z; acc[0][3] += av.x * bv.w;
      acc[1][0] += av.y * bv.x; acc[1][1] += av.y * bv.y;
      acc[1][2] += av.y * bv.z; acc[1][3] += av.y * bv.w;
    }
    __syncthreads();
  }

  float4 bias4 = *(const float4*)(bias + nq * 4);
#pragma unroll
  for (int i = 0; i < 2; ++i) {
    int t = t0 + m2 * 2 + i;
    long base = ((long)(bh * 192 + t)) * 64 + nq * 4;
    float o0 = acc[i][0] + bias4.x;
    float o1 = acc[i][1] + bias4.y;
    float o2 = acc[i][2] + bias4.z;
    float o3 = acc[i][3] + bias4.w;
    if (slot == 0) {  // fold attention scale+log2e into Q
      o0 *= ESC; o1 *= ESC; o2 *= ESC; o3 *= ESC;
    }
    if (outf) {
      float4 st = {o0, o1, o2, o3};
      *(float4*)(outf + base) = st;
    } else {
      h2v a = pkh(o0, o1), c2 = pkh(o2, o3);
      uint2 st = {__builtin_bit_cast(u32, a), __builtin_bit_cast(u32, c2)};
      *(uint2*)(outb + base) = st;
    }
  }
}

// ---------------- attention kernel ----------------
// grid = SPLIT*16*12 = 1536 blocks, 256 threads (4 waves), LDS = 25856 B.
//
// Operand-swapped scores: S^T = mfma(A=K2, B=Q*K1) puts the output with
// i in lane&15 and k in (quad, reg) -- which is EXACTLY the A-fragment
// layout for the PV matmul.  So P = exp2(S) never touches LDS: convert
// in-register with cvt_pkrtz and feed the PV mfma directly.  No barriers
// in the main loop; waves are independent (each owns a 48-k slice, all d).
// Per-wave partial O (over its k slice) is reduced across waves in a tiny
// LDS epilogue.  LDS is only used for the V2^T prologue stage + epilogue.
// BISECT NOTE: this is the round-2 PASSING source with exactly ONE change:
// V2T u16 row stride 200 -> 202 (odd dword stride -> write conflicts 8->2
// way, reads conflict-free).  Odd stride leaves rows 4B-aligned only, so
// fragment reads use u32 pairs instead of h4v (same bits).
__global__ __launch_bounds__(256, 4) void attn_kernel(
    const u16* __restrict__ Q0h, const u16* __restrict__ K1h,
    const float* __restrict__ V1f, const u16* __restrict__ K2b,
    const u16* __restrict__ V2b, float* __restrict__ Op,
    float* __restrict__ lp) {
  __shared__ __align__(16) char smem[25856];
  int bx = blockIdx.x;
  int sp = bx / 192;
  int rem = bx - sp * 192;
  int bh = rem / 12;
  int itile = rem - bh * 12;
  int i0 = itile * 16;
  int js = sp * 24;
  int tid = threadIdx.x;
  int wave = tid >> 6;
  int lane = tid & 63;
  int l15 = lane & 15;
  int quad = lane >> 4;

  // ---- prologue: stage V2^T [64 d][202 pad] u16 (natural k order)
  u16* V2T = (u16*)smem;
  {
    const u32* vsrc = (const u32*)V2b + bh * 6144;
#pragma unroll
    for (int r = 0; r < 24; ++r) {
      int idx = r * 256 + tid;
      int k = idx >> 5, d2 = idx & 31;
      u32 v = vsrc[idx];
      V2T[(d2 * 2) * 202 + k] = (u16)v;
      V2T[(d2 * 2 + 1) * 202 + k] = (u16)(v >> 16);
    }
  }
  // K2 A-fragments straight from global (rows k = w*48+nt*16+l15, kdim d)
  h8v k2f[3][2];
#pragma unroll
  for (int nt = 0; nt < 3; ++nt)
#pragma unroll
    for (int ks = 0; ks < 2; ++ks)
      k2f[nt][ks] = *(const h8v*)(K2b +
          (bh * 192 + wave * 48 + nt * 16 + l15) * 64 + ks * 32 + quad * 8);
  // Q B-fragments (kdim d = quad*8+idx (+32), col i = l15), pre-scaled ESC
  const u16* qq = Q0h + (bh * 192 + i0 + l15) * 64 + quad * 8;
  h8v qh0 = *(const h8v*)qq;
  h8v qh1 = *(const h8v*)(qq + 32);
  __syncthreads();
  // V2 B-frags for PV: grp0 k = w48+{quad*4+0..3, 16+quad*4+0..3},
  // grp1 k = w48+32+quad*4+0..3; col d = dt*16+l15.  u32 reads (stride
  // 404 B is only 4B-aligned for odd d).
  h8v v2g0[4]; h4v v2g1[4];
#pragma unroll
  for (int dt = 0; dt < 4; ++dt) {
    const char* p = smem + (dt * 16 + l15) * 404 + wave * 96 + quad * 8;
    union { h8v v; u32 w[4]; } u0;
    u0.w[0] = *(const u32*)p;        u0.w[1] = *(const u32*)(p + 4);
    u0.w[2] = *(const u32*)(p + 32); u0.w[3] = *(const u32*)(p + 36);
    v2g0[dt] = u0.v;
    union { h4v v; u32 w[2]; } u1;
    u1.w[0] = *(const u32*)(p + 64); u1.w[1] = *(const u32*)(p + 68);
    v2g1[dt] = u1.v;
  }
  __syncthreads();  // all frags in regs; smem reusable by epilogue

  f4v Oacc[4] = {};
  float lsum = 0.f;
  const u16* krow = K1h + (bh * 192 + js) * 64;
  const float* vrow = V1f + (bh * 192 + js) * 64;
  const f4v z = {0.f, 0.f, 0.f, 0.f};

#pragma unroll 1
  for (int j = 0; j < 24; ++j) {
    // B-frag of S^T: Q~[i,d]*K1[j,d] via packed f16 mul
    h8v c0 = *(const h8v*)(krow + j * 64 + quad * 8);
    h8v c1 = *(const h8v*)(krow + j * 64 + 32 + quad * 8);
    h8v B0 = qh0 * c0, B1 = qh1 * c1;
    // S^T[k=w48+nt*16+quad*4+r][i=l15], sum over d=0..63
    f4v s0 = mfma_k32(k2f[0][0], B0, z);
    f4v s1 = mfma_k32(k2f[1][0], B0, z);
    f4v s2 = mfma_k32(k2f[2][0], B0, z);
    s0 = mfma_k32(k2f[0][1], B1, s0);
    s1 = mfma_k32(k2f[1][1], B1, s1);
    s2 = mfma_k32(k2f[2][1], B1, s2);
    float p[12];
#pragma unroll
    for (int r = 0; r < 4; ++r) {
      p[r] = __builtin_amdgcn_exp2f(s0[r]);
      p[4 + r] = __builtin_amdgcn_exp2f(s1[r]);
      p[8 + r] = __builtin_amdgcn_exp2f(s2[r]);
    }
    lsum += (((p[0] + p[1]) + (p[2] + p[3])) + ((p[4] + p[5]) + (p[6] + p[7]))) +
            ((p[8] + p[9]) + (p[10] + p[11]));
    // P already in A-fragment layout: row i=l15, k in (quad, idx)
    union { h8v v; h2v h[4]; } pa0;
    pa0.h[0] = pkh(p[0], p[1]);  pa0.h[1] = pkh(p[2], p[3]);
    pa0.h[2] = pkh(p[4], p[5]);  pa0.h[3] = pkh(p[6], p[7]);
    union { h4v v; h2v h[2]; } pa1;
    pa1.h[0] = pkh(p[8], p[9]);  pa1.h[1] = pkh(p[10], p[11]);
    float v1r0 = vrow[j * 64 + l15];
    float v1r1 = vrow[j * 64 + 16 + l15];
    float v1r2 = vrow[j * 64 + 32 + l15];
    float v1r3 = vrow[j * 64 + 48 + l15];
    // W_j[i,d] over this wave's 48 k, then O += V1[j,d]*W_j
#pragma unroll
    for (int dt = 0; dt < 4; ++dt) {
      f4v w = mfma_k32(pa0.v, v2g0[dt], z);
      w = mfma_k16(pa1.v, v2g1[dt], w);
      float v1x = dt == 0 ? v1r0 : dt == 1 ? v1r1 : dt == 2 ? v1r2 : v1r3;
      Oacc[dt][0] = fmaf(v1x, w[0], Oacc[dt][0]);
      Oacc[dt][1] = fmaf(v1x, w[1], Oacc[dt][1]);
      Oacc[dt][2] = fmaf(v1x, w[2], Oacc[dt][2]);
      Oacc[dt][3] = fmaf(v1x, w[3], Oacc[dt][3]);
    }
  }

  // ---- epilogue: cross-wave k-slice reduction of O and l
  __syncthreads();  // all waves done; smem free
  float* ored = (float*)smem;            // 4 waves x [16 i][64 d] f32
  float* lred = (float*)(smem + 16384);  // 64 f32
  float* ow = ored + wave * 1024;
#pragma unroll
  for (int dt = 0; dt < 4; ++dt)
#pragma unroll
    for (int r = 0; r < 4; ++r)
      ow[(quad * 4 + r) * 64 + dt * 16 + l15] = Oacc[dt][r];
  lsum += __shfl_xor(lsum, 16);
  lsum += __shfl_xor(lsum, 32);
  if (quad == 0) lred[wave * 16 + l15] = lsum;
  __syncthreads();
  f4v s = *(const f4v*)(ored + tid * 4);
  s += *(const f4v*)(ored + 1024 + tid * 4);
  s += *(const f4v*)(ored + 2048 + tid * 4);
  s += *(const f4v*)(ored + 3072 + tid * 4);
  *(f4v*)(Op + ((long)(sp * 16 + bh) * 192 + i0) * 64 + tid * 4) = s;
  if (tid < 16)
    lp[(sp * 16 + bh) * 192 + i0 + tid] =
        lred[tid] + lred[16 + tid] + lred[32 + tid] + lred[48 + tid];
}

// ---------------- output projection (split-combine + 1/l fused) ----------
// grid = 24 mt(16) * 8 nt(64) = 192 blocks, register-dbuf staging.
__global__ __launch_bounds__(256) void outproj_kernel(
    const float* __restrict__ Op, const float* __restrict__ lp,
    const float* __restrict__ cw, const float* __restrict__ cb,
    float* __restrict__ out) {
  __shared__ float xs[32][20];   // [c][m]
  __shared__ float wsh[32][68];  // [c][n]
  __shared__ float linv[8][16];  // [h][m]
  int bx = blockIdx.x;
  int mt = bx >> 3, nt = bx & 7;
  int m0 = mt * 16;
  int b = m0 / 192;
  int t0 = m0 - b * 192;
  int n0 = nt * 64;
  int tid = threadIdx.x;

  if (tid < 128) {
    int h = tid >> 4, ml = tid & 15;
    float s = 0.f;
#pragma unroll
    for (int sp = 0; sp < SPLIT; ++sp)
      s += lp[(sp * 16 + b * 8 + h) * 192 + t0 + ml];
    linv[h][ml] = 1.0f / s;
  }

  int mA = tid >> 3, clA = (tid & 7) * 4;  // A-stage (tid<128 only)
  int nB0 = tid >> 3, nB1 = (256 + tid) >> 3;
  int m = tid >> 4, nq = tid & 15;
  float acc[4] = {};

  float4 pA[SPLIT];
  float4 pW0, pW1;
  {  // prefetch kc = 0 (h=0, d0=0)
    if (tid < 128) {
#pragma unroll
      for (int sp = 0; sp < SPLIT; ++sp)
        pA[sp] = *(const float4*)(
            Op + (long)((sp * 16 + b * 8) * 192 + t0 + mA) * 64 + clA);
    }
    pW0 = *(const float4*)(cw + (long)(n0 + nB0) * 512 + clA);
    pW1 = *(const float4*)(cw + (long)(n0 + nB1) * 512 + clA);
  }
  __syncthreads();  // linv ready

  for (int kc = 0; kc < 16; ++kc) {
    int h = kc >> 1;
    if (tid < 128) {  // combine SPLIT partials, scale 1/l, store [c][m]
      float4 s = pA[0];
#pragma unroll
      for (int sp = 1; sp < SPLIT; ++sp) {
        s.x += pA[sp].x; s.y += pA[sp].y; s.z += pA[sp].z; s.w += pA[sp].w;
      }
      float li = linv[h][mA];
      xs[clA][mA] = s.x * li; xs[clA + 1][mA] = s.y * li;
      xs[clA + 2][mA] = s.z * li; xs[clA + 3][mA] = s.w * li;
    }
    wsh[clA][nB0] = pW0.x; wsh[clA + 1][nB0] = pW0.y;
    wsh[clA + 2][nB0] = pW0.z; wsh[clA + 3][nB0] = pW0.w;
    wsh[clA][nB1] = pW1.x; wsh[clA + 1][nB1] = pW1.y;
    wsh[clA + 2][nB1] = pW1.z; wsh[clA + 3][nB1] = pW1.w;
    __syncthreads();
    if (kc < 15) {  // prefetch next kc during compute
      int h2 = (kc + 1) >> 1, d2 = ((kc + 1) & 1) * 32;
      if (tid < 128) {
#pragma unroll
        for (int sp = 0; sp < SPLIT; ++sp)
          pA[sp] = *(const float4*)(
              Op + (long)((sp * 16 + b * 8 + h2) * 192 + t0 + mA) * 64 + d2 +
              clA);
      }
      pW0 = *(const float4*)(cw + (long)(n0 + nB0) * 512 + h2 * 64 + d2 + clA);
      pW1 = *(const float4*)(cw + (long)(n0 + nB1) * 512 + h2 * 64 + d2 + clA);
    }
#pragma unroll
    for (int c = 0; c < 32; ++c) {
      float a = xs[c][m];
      float4 bv = *(const float4*)&wsh[c][nq * 4];
      acc[0] += a * bv.x; acc[1] += a * bv.y;
      acc[2] += a * bv.z; acc[3] += a * bv.w;
    }
    __syncthreads();
  }

  float4 bias = *(const float4*)(cb + n0 + nq * 4);
  float4 st;
  st.x = acc[0] + bias.x;
  st.y = acc[1] + bias.y;
  st.z = acc[2] + bias.z;
  st.w = acc[3] + bias.w;
  *(float4*)(out + (long)(b * 192 + t0 + m) * 512 + n0 + nq * 4) = st;
}

extern "C" void kernel_launch(void* const* d_in, const int* in_sizes, int n_in,
                              void* d_out, int out_size, void* d_ws, size_t ws_size,
                              hipStream_t stream) {
  const float* x0 = (const float*)d_in[0];
  const float* x1 = (const float*)d_in[1];
  const float* x2 = (const float*)d_in[2];
  const float* qw = (const float*)d_in[3];
  const float* qb = (const float*)d_in[4];
  const float* kw = (const float*)d_in[5];
  const float* kb = (const float*)d_in[6];
  const float* vw = (const float*)d_in[7];
  const float* vb = (const float*)d_in[8];
  const float* cw = (const float*)d_in[9];
  const float* cb = (const float*)d_in[10];
  float* out = (float*)d_out;

  // workspace carve
  char* ws = (char*)d_ws;
  u16* Q0h = (u16*)(ws + 0);            // 16*192*64 f16 (pre-scaled by ESC)
  u16* K1h = (u16*)(ws + 393216);       // 16*192*64 f16
  float* V1f = (float*)(ws + 786432);   // 16*192*64 f32
  u16* K2b = (u16*)(ws + 1572864);      // 16*192*64 f16
  u16* V2b = (u16*)(ws + 1966080);      // 16*192*64 f16
  float* Op = (float*)(ws + 2359296);   // SPLIT*16*192*64 f32 = 6291456 B
  float* lp = (float*)(ws + 2359296 + (size_t)SPLIT * 786432);  // SPLIT*16*192 f32

  proj_kernel<<<480, 256, 0, stream>>>(x0, x1, x2, qw, qb, kw, kb, vw, vb,
                                       Q0h, K1h, V1f, K2b, V2b);
  attn_kernel<<<SPLIT * 192, 256, 0, stream>>>(Q0h, K1h, V1f, K2b, V2b,
                                               Op, lp);
  outproj_kernel<<<192, 256, 0, stream>>>(Op, lp, cw, cb, out);
}

// Round 9
// 160.536 us; speedup vs baseline: 1.1209x; 1.0021x over previous
//
#include <hip/hip_runtime.h>

typedef float f4v __attribute__((ext_vector_type(4)));
typedef _Float16 h2v __attribute__((ext_vector_type(2)));
typedef _Float16 h4v __attribute__((ext_vector_type(4)));
typedef _Float16 h8v __attribute__((ext_vector_type(8)));
typedef __fp16 g4 __attribute__((ext_vector_type(4)));
typedef __fp16 g8 __attribute__((ext_vector_type(8)));
typedef unsigned short u16;
typedef unsigned int u32;

// B=2, T=192, C=512, H=8, HS=64, ORDER=3; scale = 1/sqrt(64) = 0.125
#define SPLIT 4
#define ESC 0.18033688011112042f  // 0.125 * log2(e), folded into Q at proj

__device__ __forceinline__ h2v pkh(float lo, float hi) {
  return __builtin_bit_cast(h2v, __builtin_amdgcn_cvt_pkrtz(lo, hi));
}
__device__ __forceinline__ f4v mfma_k32(h8v a, h8v b, f4v c) {
  return __builtin_amdgcn_mfma_f32_16x16x32_f16(
      __builtin_bit_cast(g8, a), __builtin_bit_cast(g8, b), c, 0, 0, 0);
}
__device__ __forceinline__ f4v mfma_k16(h4v a, h4v b, f4v c) {
  return __builtin_amdgcn_mfma_f32_16x16x16f16(
      __builtin_bit_cast(g4, a), __builtin_bit_cast(g4, b), c, 0, 0, 0);
}

// ---------------- projection kernel ----------------
// grid = 5 slots * 16 bh * 6 t-tiles = 480 blocks, 256 threads.
// Tile 32(t) x 64(d), K=512, register-dbuf staging.
// Outputs: Q0h/K1h/K2b/V2b as f16 (Q pre-scaled by ESC), V1f as f32
// (V1 multiplies outside MFMA -> keep full precision there).
__global__ __launch_bounds__(256) void proj_kernel(
    const float* __restrict__ x0, const float* __restrict__ x1,
    const float* __restrict__ x2,
    const float* __restrict__ qw, const float* __restrict__ qb,
    const float* __restrict__ kw, const float* __restrict__ kb,
    const float* __restrict__ vw, const float* __restrict__ vb,
    u16* __restrict__ Q0h, u16* __restrict__ K1h, float* __restrict__ V1f,
    u16* __restrict__ K2b, u16* __restrict__ V2b) {
  __shared__ float xs[32][36];   // [c][m]
  __shared__ float wsh[32][68];  // [c][n]

  int bx = blockIdx.x;
  int slot = bx / 96;
  int rem = bx - slot * 96;
  int bh = rem / 6;
  int tt = rem - bh * 6;
  int b = bh >> 3, h = bh & 7;
  int t0 = tt * 32;

  const float* x; const float* w; const float* bias; int o;
  float* outf = nullptr; u16* outb = nullptr;
  switch (slot) {
    case 0: x = x0; w = qw; bias = qb; o = 0; outb = Q0h; break;
    case 1: x = x1; w = kw; bias = kb; o = 1; outb = K1h; break;
    case 2: x = x2; w = kw; bias = kb; o = 2; outb = K2b; break;
    case 3: x = x1; w = vw; bias = vb; o = 1; outf = V1f; break;
    default: x = x2; w = vw; bias = vb; o = 2; outb = V2b; break;
  }
  x += b * 192 * 512;
  w += (h * 3 + o) * 64 * 512;
  bias += (h * 3 + o) * 64;

  int tid = threadIdx.x;
  int m2 = tid >> 4, nq = tid & 15;
  int mA = tid >> 3, clA = (tid & 7) * 4;      // A-stage coords
  int nB0 = tid >> 3, nB1 = (256 + tid) >> 3;  // B-stage coords (2 rows)
  float acc[2][4] = {};

  float4 pX, pW0, pW1;  // prefetch registers
  pX = *(const float4*)(x + (t0 + mA) * 512 + clA);
  pW0 = *(const float4*)(w + nB0 * 512 + clA);
  pW1 = *(const float4*)(w + nB1 * 512 + clA);

  for (int kc = 0; kc < 16; ++kc) {
    xs[clA][mA] = pX.x; xs[clA + 1][mA] = pX.y;
    xs[clA + 2][mA] = pX.z; xs[clA + 3][mA] = pX.w;
    wsh[clA][nB0] = pW0.x; wsh[clA + 1][nB0] = pW0.y;
    wsh[clA + 2][nB0] = pW0.z; wsh[clA + 3][nB0] = pW0.w;
    wsh[clA][nB1] = pW1.x; wsh[clA + 1][nB1] = pW1.y;
    wsh[clA + 2][nB1] = pW1.z; wsh[clA + 3][nB1] = pW1.w;
    __syncthreads();
    if (kc < 15) {  // prefetch next tile; latency hidden by compute below
      int cb0 = (kc + 1) * 32;
      pX = *(const float4*)(x + (t0 + mA) * 512 + cb0 + clA);
      pW0 = *(const float4*)(w + nB0 * 512 + cb0 + clA);
      pW1 = *(const float4*)(w + nB1 * 512 + cb0 + clA);
    }
#pragma unroll
    for (int c = 0; c < 32; ++c) {
      float2 av = *(const float2*)&xs[c][m2 * 2];
      float4 bv = *(const float4*)&wsh[c][nq * 4];
      acc[0][0] += av.x * bv.x; acc[0][1] += av.x * bv.y;
      acc[0][2] += av.x * bv.z; acc[0][3] += av.x * bv.w;
      acc[1][0] += av.y * bv.x; acc[1][1] += av.y * bv.y;
      acc[1][2] += av.y * bv.z; acc[1][3] += av.y * bv.w;
    }
    __syncthreads();
  }

  float4 bias4 = *(const float4*)(bias + nq * 4);
#pragma unroll
  for (int i = 0; i < 2; ++i) {
    int t = t0 + m2 * 2 + i;
    long base = ((long)(bh * 192 + t)) * 64 + nq * 4;
    float o0 = acc[i][0] + bias4.x;
    float o1 = acc[i][1] + bias4.y;
    float o2 = acc[i][2] + bias4.z;
    float o3 = acc[i][3] + bias4.w;
    if (slot == 0) {  // fold attention scale+log2e into Q
      o0 *= ESC; o1 *= ESC; o2 *= ESC; o3 *= ESC;
    }
    if (outf) {
      float4 st = {o0, o1, o2, o3};
      *(float4*)(outf + base) = st;
    } else {
      h2v a = pkh(o0, o1), c2 = pkh(o2, o3);
      uint2 st = {__builtin_bit_cast(u32, a), __builtin_bit_cast(u32, c2)};
      *(uint2*)(outb + base) = st;
    }
  }
}

// ---------------- attention kernel ----------------
// grid = SPLIT*16*12 = 768 blocks, 256 threads (4 waves), LDS = 25856 B.
//
// Operand-swapped scores: S^T = mfma(A=K2, B=Q*K1) puts the output with
// i in lane&15 and k in (quad, reg) -- which is EXACTLY the A-fragment
// layout for the PV matmul.  So P = exp2(S) never touches LDS: convert
// in-register with cvt_pkrtz and feed the PV mfma directly.  No barriers
// in the main loop; waves are independent (each owns a 48-k slice, all d).
// Per-wave partial O (over its k slice) is reduced across waves in a tiny
// LDS epilogue.  LDS is only used for the V2^T prologue stage + epilogue.
// BISECT NOTE: this is the round-6 PASSING source with exactly ONE change:
// SPLIT 8 -> 4 (j-loop 24 -> 48, grid halves).  Same single-chain loop
// body (ILP-doubling variants miscompile -- rounds 3/4/7/8); prologue
// amortizes over 2x work, outproj combines 4 partials instead of 8.
__global__ __launch_bounds__(256, 4) void attn_kernel(
    const u16* __restrict__ Q0h, const u16* __restrict__ K1h,
    const float* __restrict__ V1f, const u16* __restrict__ K2b,
    const u16* __restrict__ V2b, float* __restrict__ Op,
    float* __restrict__ lp) {
  __shared__ __align__(16) char smem[25856];
  int bx = blockIdx.x;
  int sp = bx / 192;
  int rem = bx - sp * 192;
  int bh = rem / 12;
  int itile = rem - bh * 12;
  int i0 = itile * 16;
  int js = sp * 48;
  int tid = threadIdx.x;
  int wave = tid >> 6;
  int lane = tid & 63;
  int l15 = lane & 15;
  int quad = lane >> 4;

  // ---- prologue: stage V2^T [64 d][202 pad] u16 (natural k order)
  u16* V2T = (u16*)smem;
  {
    const u32* vsrc = (const u32*)V2b + bh * 6144;
#pragma unroll
    for (int r = 0; r < 24; ++r) {
      int idx = r * 256 + tid;
      int k = idx >> 5, d2 = idx & 31;
      u32 v = vsrc[idx];
      V2T[(d2 * 2) * 202 + k] = (u16)v;
      V2T[(d2 * 2 + 1) * 202 + k] = (u16)(v >> 16);
    }
  }
  // K2 A-fragments straight from global (rows k = w*48+nt*16+l15, kdim d)
  h8v k2f[3][2];
#pragma unroll
  for (int nt = 0; nt < 3; ++nt)
#pragma unroll
    for (int ks = 0; ks < 2; ++ks)
      k2f[nt][ks] = *(const h8v*)(K2b +
          (bh * 192 + wave * 48 + nt * 16 + l15) * 64 + ks * 32 + quad * 8);
  // Q B-fragments (kdim d = quad*8+idx (+32), col i = l15), pre-scaled ESC
  const u16* qq = Q0h + (bh * 192 + i0 + l15) * 64 + quad * 8;
  h8v qh0 = *(const h8v*)qq;
  h8v qh1 = *(const h8v*)(qq + 32);
  __syncthreads();
  // V2 B-frags for PV: grp0 k = w48+{quad*4+0..3, 16+quad*4+0..3},
  // grp1 k = w48+32+quad*4+0..3; col d = dt*16+l15.  u32 reads (stride
  // 404 B is only 4B-aligned for odd d).
  h8v v2g0[4]; h4v v2g1[4];
#pragma unroll
  for (int dt = 0; dt < 4; ++dt) {
    const char* p = smem + (dt * 16 + l15) * 404 + wave * 96 + quad * 8;
    union { h8v v; u32 w[4]; } u0;
    u0.w[0] = *(const u32*)p;        u0.w[1] = *(const u32*)(p + 4);
    u0.w[2] = *(const u32*)(p + 32); u0.w[3] = *(const u32*)(p + 36);
    v2g0[dt] = u0.v;
    union { h4v v; u32 w[2]; } u1;
    u1.w[0] = *(const u32*)(p + 64); u1.w[1] = *(const u32*)(p + 68);
    v2g1[dt] = u1.v;
  }
  __syncthreads();  // all frags in regs; smem reusable by epilogue

  f4v Oacc[4] = {};
  float lsum = 0.f;
  const u16* krow = K1h + (bh * 192 + js) * 64;
  const float* vrow = V1f + (bh * 192 + js) * 64;
  const f4v z = {0.f, 0.f, 0.f, 0.f};

#pragma unroll 1
  for (int j = 0; j < 48; ++j) {
    // B-frag of S^T: Q~[i,d]*K1[j,d] via packed f16 mul
    h8v c0 = *(const h8v*)(krow + j * 64 + quad * 8);
    h8v c1 = *(const h8v*)(krow + j * 64 + 32 + quad * 8);
    h8v B0 = qh0 * c0, B1 = qh1 * c1;
    // S^T[k=w48+nt*16+quad*4+r][i=l15], sum over d=0..63
    f4v s0 = mfma_k32(k2f[0][0], B0, z);
    f4v s1 = mfma_k32(k2f[1][0], B0, z);
    f4v s2 = mfma_k32(k2f[2][0], B0, z);
    s0 = mfma_k32(k2f[0][1], B1, s0);
    s1 = mfma_k32(k2f[1][1], B1, s1);
    s2 = mfma_k32(k2f[2][1], B1, s2);
    float p[12];
#pragma unroll
    for (int r = 0; r < 4; ++r) {
      p[r] = __builtin_amdgcn_exp2f(s0[r]);
      p[4 + r] = __builtin_amdgcn_exp2f(s1[r]);
      p[8 + r] = __builtin_amdgcn_exp2f(s2[r]);
    }
    lsum += (((p[0] + p[1]) + (p[2] + p[3])) + ((p[4] + p[5]) + (p[6] + p[7]))) +
            ((p[8] + p[9]) + (p[10] + p[11]));
    // P already in A-fragment layout: row i=l15, k in (quad, idx)
    union { h8v v; h2v h[4]; } pa0;
    pa0.h[0] = pkh(p[0], p[1]);  pa0.h[1] = pkh(p[2], p[3]);
    pa0.h[2] = pkh(p[4], p[5]);  pa0.h[3] = pkh(p[6], p[7]);
    union { h4v v; h2v h[2]; } pa1;
    pa1.h[0] = pkh(p[8], p[9]);  pa1.h[1] = pkh(p[10], p[11]);
    float v1r0 = vrow[j * 64 + l15];
    float v1r1 = vrow[j * 64 + 16 + l15];
    float v1r2 = vrow[j * 64 + 32 + l15];
    float v1r3 = vrow[j * 64 + 48 + l15];
    // W_j[i,d] over this wave's 48 k, then O += V1[j,d]*W_j
#pragma unroll
    for (int dt = 0; dt < 4; ++dt) {
      f4v w = mfma_k32(pa0.v, v2g0[dt], z);
      w = mfma_k16(pa1.v, v2g1[dt], w);
      float v1x = dt == 0 ? v1r0 : dt == 1 ? v1r1 : dt == 2 ? v1r2 : v1r3;
      Oacc[dt][0] = fmaf(v1x, w[0], Oacc[dt][0]);
      Oacc[dt][1] = fmaf(v1x, w[1], Oacc[dt][1]);
      Oacc[dt][2] = fmaf(v1x, w[2], Oacc[dt][2]);
      Oacc[dt][3] = fmaf(v1x, w[3], Oacc[dt][3]);
    }
  }

  // ---- epilogue: cross-wave k-slice reduction of O and l
  __syncthreads();  // all waves done; smem free
  float* ored = (float*)smem;            // 4 waves x [16 i][64 d] f32
  float* lred = (float*)(smem + 16384);  // 64 f32
  float* ow = ored + wave * 1024;
#pragma unroll
  for (int dt = 0; dt < 4; ++dt)
#pragma unroll
    for (int r = 0; r < 4; ++r)
      ow[(quad * 4 + r) * 64 + dt * 16 + l15] = Oacc[dt][r];
  lsum += __shfl_xor(lsum, 16);
  lsum += __shfl_xor(lsum, 32);
  if (quad == 0) lred[wave * 16 + l15] = lsum;
  __syncthreads();
  f4v s = *(const f4v*)(ored + tid * 4);
  s += *(const f4v*)(ored + 1024 + tid * 4);
  s += *(const f4v*)(ored + 2048 + tid * 4);
  s += *(const f4v*)(ored + 3072 + tid * 4);
  *(f4v*)(Op + ((long)(sp * 16 + bh) * 192 + i0) * 64 + tid * 4) = s;
  if (tid < 16)
    lp[(sp * 16 + bh) * 192 + i0 + tid] =
        lred[tid] + lred[16 + tid] + lred[32 + tid] + lred[48 + tid];
}

// ---------------- output projection (split-combine + 1/l fused) ----------
// grid = 24 mt(16) * 8 nt(64) = 192 blocks, register-dbuf staging.
__global__ __launch_bounds__(256) void outproj_kernel(
    const float* __restrict__ Op, const float* __restrict__ lp,
    const float* __restrict__ cw, const float* __restrict__ cb,
    float* __restrict__ out) {
  __shared__ float xs[32][20];   // [c][m]
  __shared__ float wsh[32][68];  // [c][n]
  __shared__ float linv[8][16];  // [h][m]
  int bx = blockIdx.x;
  int mt = bx >> 3, nt = bx & 7;
  int m0 = mt * 16;
  int b = m0 / 192;
  int t0 = m0 - b * 192;
  int n0 = nt * 64;
  int tid = threadIdx.x;

  if (tid < 128) {
    int h = tid >> 4, ml = tid & 15;
    float s = 0.f;
#pragma unroll
    for (int sp = 0; sp < SPLIT; ++sp)
      s += lp[(sp * 16 + b * 8 + h) * 192 + t0 + ml];
    linv[h][ml] = 1.0f / s;
  }

  int mA = tid >> 3, clA = (tid & 7) * 4;  // A-stage (tid<128 only)
  int nB0 = tid >> 3, nB1 = (256 + tid) >> 3;
  int m = tid >> 4, nq = tid & 15;
  float acc[4] = {};

  float4 pA[SPLIT];
  float4 pW0, pW1;
  {  // prefetch kc = 0 (h=0, d0=0)
    if (tid < 128) {
#pragma unroll
      for (int sp = 0; sp < SPLIT; ++sp)
        pA[sp] = *(const float4*)(
            Op + (long)((sp * 16 + b * 8) * 192 + t0 + mA) * 64 + clA);
    }
    pW0 = *(const float4*)(cw + (long)(n0 + nB0) * 512 + clA);
    pW1 = *(const float4*)(cw + (long)(n0 + nB1) * 512 + clA);
  }
  __syncthreads();  // linv ready

  for (int kc = 0; kc < 16; ++kc) {
    int h = kc >> 1;
    if (tid < 128) {  // combine SPLIT partials, scale 1/l, store [c][m]
      float4 s = pA[0];
#pragma unroll
      for (int sp = 1; sp < SPLIT; ++sp) {
        s.x += pA[sp].x; s.y += pA[sp].y; s.z += pA[sp].z; s.w += pA[sp].w;
      }
      float li = linv[h][mA];
      xs[clA][mA] = s.x * li; xs[clA + 1][mA] = s.y * li;
      xs[clA + 2][mA] = s.z * li; xs[clA + 3][mA] = s.w * li;
    }
    wsh[clA][nB0] = pW0.x; wsh[clA + 1][nB0] = pW0.y;
    wsh[clA + 2][nB0] = pW0.z; wsh[clA + 3][nB0] = pW0.w;
    wsh[clA][nB1] = pW1.x; wsh[clA + 1][nB1] = pW1.y;
    wsh[clA + 2][nB1] = pW1.z; wsh[clA + 3][nB1] = pW1.w;
    __syncthreads();
    if (kc < 15) {  // prefetch next kc during compute
      int h2 = (kc + 1) >> 1, d2 = ((kc + 1) & 1) * 32;
      if (tid < 128) {
#pragma unroll
        for (int sp = 0; sp < SPLIT; ++sp)
          pA[sp] = *(const float4*)(
              Op + (long)((sp * 16 + b * 8 + h2) * 192 + t0 + mA) * 64 + d2 +
              clA);
      }
      pW0 = *(const float4*)(cw + (long)(n0 + nB0) * 512 + h2 * 64 + d2 + clA);
      pW1 = *(const float4*)(cw + (long)(n0 + nB1) * 512 + h2 * 64 + d2 + clA);
    }
#pragma unroll
    for (int c = 0; c < 32; ++c) {
      float a = xs[c][m];
      float4 bv = *(const float4*)&wsh[c][nq * 4];
      acc[0] += a * bv.x; acc[1] += a * bv.y;
      acc[2] += a * bv.z; acc[3] += a * bv.w;
    }
    __syncthreads();
  }

  float4 bias = *(const float4*)(cb + n0 + nq * 4);
  float4 st;
  st.x = acc[0] + bias.x;
  st.y = acc[1] + bias.y;
  st.z = acc[2] + bias.z;
  st.w = acc[3] + bias.w;
  *(float4*)(out + (long)(b * 192 + t0 + m) * 512 + n0 + nq * 4) = st;
}

extern "C" void kernel_launch(void* const* d_in, const int* in_sizes, int n_in,
                              void* d_out, int out_size, void* d_ws, size_t ws_size,
                              hipStream_t stream) {
  const float* x0 = (const float*)d_in[0];
  const float* x1 = (const float*)d_in[1];
  const float* x2 = (const float*)d_in[2];
  const float* qw = (const float*)d_in[3];
  const float* qb = (const float*)d_in[4];
  const float* kw = (const float*)d_in[5];
  const float* kb = (const float*)d_in[6];
  const float* vw = (const float*)d_in[7];
  const float* vb = (const float*)d_in[8];
  const float* cw = (const float*)d_in[9];
  const float* cb = (const float*)d_in[10];
  float* out = (float*)d_out;

  // workspace carve
  char* ws = (char*)d_ws;
  u16* Q0h = (u16*)(ws + 0);            // 16*192*64 f16 (pre-scaled by ESC)
  u16* K1h = (u16*)(ws + 393216);       // 16*192*64 f16
  float* V1f = (float*)(ws + 786432);   // 16*192*64 f32
  u16* K2b = (u16*)(ws + 1572864);      // 16*192*64 f16
  u16* V2b = (u16*)(ws + 1966080);      // 16*192*64 f16
  float* Op = (float*)(ws + 2359296);   // SPLIT*16*192*64 f32 = 3145728 B
  float* lp = (float*)(ws + 2359296 + (size_t)SPLIT * 786432);  // SPLIT*16*192 f32

  proj_kernel<<<480, 256, 0, stream>>>(x0, x1, x2, qw, qb, kw, kb, vw, vb,
                                       Q0h, K1h, V1f, K2b, V2b);
  attn_kernel<<<SPLIT * 192, 256, 0, stream>>>(Q0h, K1h, V1f, K2b, V2b,
                                               Op, lp);
  outproj_kernel<<<192, 256, 0, stream>>>(Op, lp, cw, cb, out);
}

// Round 11
// 158.884 us; speedup vs baseline: 1.1325x; 1.0104x over previous
//
#include <hip/hip_runtime.h>

typedef float f4v __attribute__((ext_vector_type(4)));
typedef _Float16 h2v __attribute__((ext_vector_type(2)));
typedef _Float16 h4v __attribute__((ext_vector_type(4)));
typedef _Float16 h8v __attribute__((ext_vector_type(8)));
typedef __fp16 g4 __attribute__((ext_vector_type(4)));
typedef __fp16 g8 __attribute__((ext_vector_type(8)));
typedef unsigned short u16;
typedef unsigned int u32;

// B=2, T=192, C=512, H=8, HS=64, ORDER=3; scale = 1/sqrt(64) = 0.125
#define SPLIT 4
#define ESC 0.18033688011112042f  // 0.125 * log2(e), folded into Q at proj

__device__ __forceinline__ h2v pkh(float lo, float hi) {
  return __builtin_bit_cast(h2v, __builtin_amdgcn_cvt_pkrtz(lo, hi));
}
__device__ __forceinline__ f4v mfma_k32(h8v a, h8v b, f4v c) {
  return __builtin_amdgcn_mfma_f32_16x16x32_f16(
      __builtin_bit_cast(g8, a), __builtin_bit_cast(g8, b), c, 0, 0, 0);
}
__device__ __forceinline__ f4v mfma_k16(h4v a, h4v b, f4v c) {
  return __builtin_amdgcn_mfma_f32_16x16x16f16(
      __builtin_bit_cast(g4, a), __builtin_bit_cast(g4, b), c, 0, 0, 0);
}

// ---------------- projection kernel ----------------
// grid = 5 slots * 16 bh * 6 t-tiles = 480 blocks, 256 threads.
// Tile 32(t) x 64(d), K=512, register-dbuf staging.
// Outputs: Q0h/K1h/K2b/V2b as f16 (Q pre-scaled by ESC), V1f as f32
// (V1 multiplies outside MFMA -> keep full precision there).
__global__ __launch_bounds__(256) void proj_kernel(
    const float* __restrict__ x0, const float* __restrict__ x1,
    const float* __restrict__ x2,
    const float* __restrict__ qw, const float* __restrict__ qb,
    const float* __restrict__ kw, const float* __restrict__ kb,
    const float* __restrict__ vw, const float* __restrict__ vb,
    u16* __restrict__ Q0h, u16* __restrict__ K1h, float* __restrict__ V1f,
    u16* __restrict__ K2b, u16* __restrict__ V2b) {
  __shared__ float xs[32][36];   // [c][m]
  __shared__ float wsh[32][68];  // [c][n]

  int bx = blockIdx.x;
  int slot = bx / 96;
  int rem = bx - slot * 96;
  int bh = rem / 6;
  int tt = rem - bh * 6;
  int b = bh >> 3, h = bh & 7;
  int t0 = tt * 32;

  const float* x; const float* w; const float* bias; int o;
  float* outf = nullptr; u16* outb = nullptr;
  switch (slot) {
    case 0: x = x0; w = qw; bias = qb; o = 0; outb = Q0h; break;
    case 1: x = x1; w = kw; bias = kb; o = 1; outb = K1h; break;
    case 2: x = x2; w = kw; bias = kb; o = 2; outb = K2b; break;
    case 3: x = x1; w = vw; bias = vb; o = 1; outf = V1f; break;
    default: x = x2; w = vw; bias = vb; o = 2; outb = V2b; break;
  }
  x += b * 192 * 512;
  w += (h * 3 + o) * 64 * 512;
  bias += (h * 3 + o) * 64;

  int tid = threadIdx.x;
  int m2 = tid >> 4, nq = tid & 15;
  int mA = tid >> 3, clA = (tid & 7) * 4;      // A-stage coords
  int nB0 = tid >> 3, nB1 = (256 + tid) >> 3;  // B-stage coords (2 rows)
  float acc[2][4] = {};

  float4 pX, pW0, pW1;  // prefetch registers
  pX = *(const float4*)(x + (t0 + mA) * 512 + clA);
  pW0 = *(const float4*)(w + nB0 * 512 + clA);
  pW1 = *(const float4*)(w + nB1 * 512 + clA);

  for (int kc = 0; kc < 16; ++kc) {
    xs[clA][mA] = pX.x; xs[clA + 1][mA] = pX.y;
    xs[clA + 2][mA] = pX.z; xs[clA + 3][mA] = pX.w;
    wsh[clA][nB0] = pW0.x; wsh[clA + 1][nB0] = pW0.y;
    wsh[clA + 2][nB0] = pW0.z; wsh[clA + 3][nB0] = pW0.w;
    wsh[clA][nB1] = pW1.x; wsh[clA + 1][nB1] = pW1.y;
    wsh[clA + 2][nB1] = pW1.z; wsh[clA + 3][nB1] = pW1.w;
    __syncthreads();
    if (kc < 15) {  // prefetch next tile; latency hidden by compute below
      int cb0 = (kc + 1) * 32;
      pX = *(const float4*)(x + (t0 + mA) * 512 + cb0 + clA);
      pW0 = *(const float4*)(w + nB0 * 512 + cb0 + clA);
      pW1 = *(const float4*)(w + nB1 * 512 + cb0 + clA);
    }
#pragma unroll
    for (int c = 0; c < 32; ++c) {
      float2 av = *(const float2*)&xs[c][m2 * 2];
      float4 bv = *(const float4*)&wsh[c][nq * 4];
      acc[0][0] += av.x * bv.x; acc[0][1] += av.x * bv.y;
      acc[0][2] += av.x * bv.z; acc[0][3] += av.x * bv.w;
      acc[1][0] += av.y * bv.x; acc[1][1] += av.y * bv.y;
      acc[1][2] += av.y * bv.z; acc[1][3] += av.y * bv.w;
    }
    __syncthreads();
  }

  float4 bias4 = *(const float4*)(bias + nq * 4);
#pragma unroll
  for (int i = 0; i < 2; ++i) {
    int t = t0 + m2 * 2 + i;
    long base = ((long)(bh * 192 + t)) * 64 + nq * 4;
    float o0 = acc[i][0] + bias4.x;
    float o1 = acc[i][1] + bias4.y;
    float o2 = acc[i][2] + bias4.z;
    float o3 = acc[i][3] + bias4.w;
    if (slot == 0) {  // fold attention scale+log2e into Q
      o0 *= ESC; o1 *= ESC; o2 *= ESC; o3 *= ESC;
    }
    if (outf) {
      float4 st = {o0, o1, o2, o3};
      *(float4*)(outf + base) = st;
    } else {
      h2v a = pkh(o0, o1), c2 = pkh(o2, o3);
      uint2 st = {__builtin_bit_cast(u32, a), __builtin_bit_cast(u32, c2)};
      *(uint2*)(outb + base) = st;
    }
  }
}

// ---------------- attention kernel ----------------
// grid = SPLIT*16*12 = 768 blocks, 256 threads (4 waves), LDS = 44288 B.
//
// Operand-swapped scores: S^T = mfma(A=K2, B=Q*K1) puts the output with
// i in lane&15 and k in (quad, reg) -- which is EXACTLY the A-fragment
// layout for the PV matmul.  So P = exp2(S) never touches LDS: convert
// in-register with cvt_pkrtz and feed the PV mfma directly.  No barriers
// in the main loop; waves are independent (each owns a 48-k slice, all d).
// BISECT NOTE: round-9 PASSING source with exactly ONE unit changed:
// K1/V1 are cooperatively staged into LDS in the prologue (two linear
// copies) and the j-loop reads them via ds_read instead of global loads.
// Same values, same FP order, same single-chain loop body (ILP-doubling
// variants miscompile -- rounds 3/4/7/8) -> bit-exact output.  This
// removes the ~200-300cy vmcnt stall at the top of every j iteration
// (the latency bottleneck: both pipes <40% busy in r9).
__global__ __launch_bounds__(256, 4) void attn_kernel(
    const u16* __restrict__ Q0h, const u16* __restrict__ K1h,
    const float* __restrict__ V1f, const u16* __restrict__ K2b,
    const u16* __restrict__ V2b, float* __restrict__ Op,
    float* __restrict__ lp) {
  __shared__ __align__(16) char smem[44288];
  int bx = blockIdx.x;
  int sp = bx / 192;
  int rem = bx - sp * 192;
  int bh = rem / 12;
  int itile = rem - bh * 12;
  int i0 = itile * 16;
  int js = sp * 48;
  int tid = threadIdx.x;
  int wave = tid >> 6;
  int lane = tid & 63;
  int l15 = lane & 15;
  int quad = lane >> 4;

  u16* K1s = (u16*)(smem + 25856);   // [48 j][64 d] u16 f16, 6144 B
  float* V1s = (float*)(smem + 32000);  // [48 j][64 d] f32, 12288 B

  // ---- prologue: stage V2^T [64 d][202 pad] u16 (natural k order)
  u16* V2T = (u16*)smem;
  {
    const u32* vsrc = (const u32*)V2b + bh * 6144;
#pragma unroll
    for (int r = 0; r < 24; ++r) {
      int idx = r * 256 + tid;
      int k = idx >> 5, d2 = idx & 31;
      u32 v = vsrc[idx];
      V2T[(d2 * 2) * 202 + k] = (u16)v;
      V2T[(d2 * 2 + 1) * 202 + k] = (u16)(v >> 16);
    }
    // stage K1 rows js..js+47 (linear copy, 768 uint2)
    const uint2* ksrc = (const uint2*)(K1h + (bh * 192 + js) * 64);
#pragma unroll
    for (int r = 0; r < 3; ++r)
      ((uint2*)K1s)[r * 256 + tid] = ksrc[r * 256 + tid];
    // stage V1 rows js..js+47 (linear copy, 768 float4)
    const float4* vsrcp = (const float4*)(V1f + (bh * 192 + js) * 64);
#pragma unroll
    for (int r = 0; r < 3; ++r)
      ((float4*)V1s)[r * 256 + tid] = vsrcp[r * 256 + tid];
  }
  // K2 A-fragments straight from global (rows k = w*48+nt*16+l15, kdim d)
  h8v k2f[3][2];
#pragma unroll
  for (int nt = 0; nt < 3; ++nt)
#pragma unroll
    for (int ks = 0; ks < 2; ++ks)
      k2f[nt][ks] = *(const h8v*)(K2b +
          (bh * 192 + wave * 48 + nt * 16 + l15) * 64 + ks * 32 + quad * 8);
  // Q B-fragments (kdim d = quad*8+idx (+32), col i = l15), pre-scaled ESC
  const u16* qq = Q0h + (bh * 192 + i0 + l15) * 64 + quad * 8;
  h8v qh0 = *(const h8v*)qq;
  h8v qh1 = *(const h8v*)(qq + 32);
  __syncthreads();
  // V2 B-frags for PV: grp0 k = w48+{quad*4+0..3, 16+quad*4+0..3},
  // grp1 k = w48+32+quad*4+0..3; col d = dt*16+l15.  u32 reads (stride
  // 404 B is only 4B-aligned for odd d).
  h8v v2g0[4]; h4v v2g1[4];
#pragma unroll
  for (int dt = 0; dt < 4; ++dt) {
    const char* p = smem + (dt * 16 + l15) * 404 + wave * 96 + quad * 8;
    union { h8v v; u32 w[4]; } u0;
    u0.w[0] = *(const u32*)p;        u0.w[1] = *(const u32*)(p + 4);
    u0.w[2] = *(const u32*)(p + 32); u0.w[3] = *(const u32*)(p + 36);
    v2g0[dt] = u0.v;
    union { h4v v; u32 w[2]; } u1;
    u1.w[0] = *(const u32*)(p + 64); u1.w[1] = *(const u32*)(p + 68);
    v2g1[dt] = u1.v;
  }
  __syncthreads();  // all frags in regs; K1s/V1s staged; V2T reusable

  f4v Oacc[4] = {};
  float lsum = 0.f;
  const f4v z = {0.f, 0.f, 0.f, 0.f};

#pragma unroll 1
  for (int j = 0; j < 48; ++j) {
    // B-frag of S^T: Q~[i,d]*K1[j,d] via packed f16 mul (K1 from LDS)
    h8v c0 = *(const h8v*)(K1s + j * 64 + quad * 8);
    h8v c1 = *(const h8v*)(K1s + j * 64 + 32 + quad * 8);
    h8v B0 = qh0 * c0, B1 = qh1 * c1;
    // S^T[k=w48+nt*16+quad*4+r][i=l15], sum over d=0..63
    f4v s0 = mfma_k32(k2f[0][0], B0, z);
    f4v s1 = mfma_k32(k2f[1][0], B0, z);
    f4v s2 = mfma_k32(k2f[2][0], B0, z);
    s0 = mfma_k32(k2f[0][1], B1, s0);
    s1 = mfma_k32(k2f[1][1], B1, s1);
    s2 = mfma_k32(k2f[2][1], B1, s2);
    float p[12];
#pragma unroll
    for (int r = 0; r < 4; ++r) {
      p[r] = __builtin_amdgcn_exp2f(s0[r]);
      p[4 + r] = __builtin_amdgcn_exp2f(s1[r]);
      p[8 + r] = __builtin_amdgcn_exp2f(s2[r]);
    }
    lsum += (((p[0] + p[1]) + (p[2] + p[3])) + ((p[4] + p[5]) + (p[6] + p[7]))) +
            ((p[8] + p[9]) + (p[10] + p[11]));
    // P already in A-fragment layout: row i=l15, k in (quad, idx)
    union { h8v v; h2v h[4]; } pa0;
    pa0.h[0] = pkh(p[0], p[1]);  pa0.h[1] = pkh(p[2], p[3]);
    pa0.h[2] = pkh(p[4], p[5]);  pa0.h[3] = pkh(p[6], p[7]);
    union { h4v v; h2v h[2]; } pa1;
    pa1.h[0] = pkh(p[8], p[9]);  pa1.h[1] = pkh(p[10], p[11]);
    float v1r0 = V1s[j * 64 + l15];
    float v1r1 = V1s[j * 64 + 16 + l15];
    float v1r2 = V1s[j * 64 + 32 + l15];
    float v1r3 = V1s[j * 64 + 48 + l15];
    // W_j[i,d] over this wave's 48 k, then O += V1[j,d]*W_j
#pragma unroll
    for (int dt = 0; dt < 4; ++dt) {
      f4v w = mfma_k32(pa0.v, v2g0[dt], z);
      w = mfma_k16(pa1.v, v2g1[dt], w);
      float v1x = dt == 0 ? v1r0 : dt == 1 ? v1r1 : dt == 2 ? v1r2 : v1r3;
      Oacc[dt][0] = fmaf(v1x, w[0], Oacc[dt][0]);
      Oacc[dt][1] = fmaf(v1x, w[1], Oacc[dt][1]);
      Oacc[dt][2] = fmaf(v1x, w[2], Oacc[dt][2]);
      Oacc[dt][3] = fmaf(v1x, w[3], Oacc[dt][3]);
    }
  }

  // ---- epilogue: cross-wave k-slice reduction of O and l
  __syncthreads();  // all waves done; smem free
  float* ored = (float*)smem;            // 4 waves x [16 i][64 d] f32
  float* lred = (float*)(smem + 16384);  // 64 f32
  float* ow = ored + wave * 1024;
#pragma unroll
  for (int dt = 0; dt < 4; ++dt)
#pragma unroll
    for (int r = 0; r < 4; ++r)
      ow[(quad * 4 + r) * 64 + dt * 16 + l15] = Oacc[dt][r];
  lsum += __shfl_xor(lsum, 16);
  lsum += __shfl_xor(lsum, 32);
  if (quad == 0) lred[wave * 16 + l15] = lsum;
  __syncthreads();
  f4v s = *(const f4v*)(ored + tid * 4);
  s += *(const f4v*)(ored + 1024 + tid * 4);
  s += *(const f4v*)(ored + 2048 + tid * 4);
  s += *(const f4v*)(ored + 3072 + tid * 4);
  *(f4v*)(Op + ((long)(sp * 16 + bh) * 192 + i0) * 64 + tid * 4) = s;
  if (tid < 16)
    lp[(sp * 16 + bh) * 192 + i0 + tid] =
        lred[tid] + lred[16 + tid] + lred[32 + tid] + lred[48 + tid];
}

// ---------------- output projection (split-combine + 1/l fused) ----------
// grid = 24 mt(16) * 8 nt(64) = 192 blocks, register-dbuf staging.
__global__ __launch_bounds__(256) void outproj_kernel(
    const float* __restrict__ Op, const float* __restrict__ lp,
    const float* __restrict__ cw, const float* __restrict__ cb,
    float* __restrict__ out) {
  __shared__ float xs[32][20];   // [c][m]
  __shared__ float wsh[32][68];  // [c][n]
  __shared__ float linv[8][16];  // [h][m]
  int bx = blockIdx.x;
  int mt = bx >> 3, nt = bx & 7;
  int m0 = mt * 16;
  int b = m0 / 192;
  int t0 = m0 - b * 192;
  int n0 = nt * 64;
  int tid = threadIdx.x;

  if (tid < 128) {
    int h = tid >> 4, ml = tid & 15;
    float s = 0.f;
#pragma unroll
    for (int sp = 0; sp < SPLIT; ++sp)
      s += lp[(sp * 16 + b * 8 + h) * 192 + t0 + ml];
    linv[h][ml] = 1.0f / s;
  }

  int mA = tid >> 3, clA = (tid & 7) * 4;  // A-stage (tid<128 only)
  int nB0 = tid >> 3, nB1 = (256 + tid) >> 3;
  int m = tid >> 4, nq = tid & 15;
  float acc[4] = {};

  float4 pA[SPLIT];
  float4 pW0, pW1;
  {  // prefetch kc = 0 (h=0, d0=0)
    if (tid < 128) {
#pragma unroll
      for (int sp = 0; sp < SPLIT; ++sp)
        pA[sp] = *(const float4*)(
            Op + (long)((sp * 16 + b * 8) * 192 + t0 + mA) * 64 + clA);
    }
    pW0 = *(const float4*)(cw + (long)(n0 + nB0) * 512 + clA);
    pW1 = *(const float4*)(cw + (long)(n0 + nB1) * 512 + clA);
  }
  __syncthreads();  // linv ready

  for (int kc = 0; kc < 16; ++kc) {
    int h = kc >> 1;
    if (tid < 128) {  // combine SPLIT partials, scale 1/l, store [c][m]
      float4 s = pA[0];
#pragma unroll
      for (int sp = 1; sp < SPLIT; ++sp) {
        s.x += pA[sp].x; s.y += pA[sp].y; s.z += pA[sp].z; s.w += pA[sp].w;
      }
      float li = linv[h][mA];
      xs[clA][mA] = s.x * li; xs[clA + 1][mA] = s.y * li;
      xs[clA + 2][mA] = s.z * li; xs[clA + 3][mA] = s.w * li;
    }
    wsh[clA][nB0] = pW0.x; wsh[clA + 1][nB0] = pW0.y;
    wsh[clA + 2][nB0] = pW0.z; wsh[clA + 3][nB0] = pW0.w;
    wsh[clA][nB1] = pW1.x; wsh[clA + 1][nB1] = pW1.y;
    wsh[clA + 2][nB1] = pW1.z; wsh[clA + 3][nB1] = pW1.w;
    __syncthreads();
    if (kc < 15) {  // prefetch next kc during compute
      int h2 = (kc + 1) >> 1, d2 = ((kc + 1) & 1) * 32;
      if (tid < 128) {
#pragma unroll
        for (int sp = 0; sp < SPLIT; ++sp)
          pA[sp] = *(const float4*)(
              Op + (long)((sp * 16 + b * 8 + h2) * 192 + t0 + mA) * 64 + d2 +
              clA);
      }
      pW0 = *(const float4*)(cw + (long)(n0 + nB0) * 512 + h2 * 64 + d2 + clA);
      pW1 = *(const float4*)(cw + (long)(n0 + nB1) * 512 + h2 * 64 + d2 + clA);
    }
#pragma unroll
    for (int c = 0; c < 32; ++c) {
      float a = xs[c][m];
      float4 bv = *(const float4*)&wsh[c][nq * 4];
      acc[0] += a * bv.x; acc[1] += a * bv.y;
      acc[2] += a * bv.z; acc[3] += a * bv.w;
    }
    __syncthreads();
  }

  float4 bias = *(const float4*)(cb + n0 + nq * 4);
  float4 st;
  st.x = acc[0] + bias.x;
  st.y = acc[1] + bias.y;
  st.z = acc[2] + bias.z;
  st.w = acc[3] + bias.w;
  *(float4*)(out + (long)(b * 192 + t0 + m) * 512 + n0 + nq * 4) = st;
}

extern "C" void kernel_launch(void* const* d_in, const int* in_sizes, int n_in,
                              void* d_out, int out_size, void* d_ws, size_t ws_size,
                              hipStream_t stream) {
  const float* x0 = (const float*)d_in[0];
  const float* x1 = (const float*)d_in[1];
  const float* x2 = (const float*)d_in[2];
  const float* qw = (const float*)d_in[3];
  const float* qb = (const float*)d_in[4];
  const float* kw = (const float*)d_in[5];
  const float* kb = (const float*)d_in[6];
  const float* vw = (const float*)d_in[7];
  const float* vb = (const float*)d_in[8];
  const float* cw = (const float*)d_in[9];
  const float* cb = (const float*)d_in[10];
  float* out = (float*)d_out;

  // workspace carve
  char* ws = (char*)d_ws;
  u16* Q0h = (u16*)(ws + 0);            // 16*192*64 f16 (pre-scaled by ESC)
  u16* K1h = (u16*)(ws + 393216);       // 16*192*64 f16
  float* V1f = (float*)(ws + 786432);   // 16*192*64 f32
  u16* K2b = (u16*)(ws + 1572864);      // 16*192*64 f16
  u16* V2b = (u16*)(ws + 1966080);      // 16*192*64 f16
  float* Op = (float*)(ws + 2359296);   // SPLIT*16*192*64 f32 = 3145728 B
  float* lp = (float*)(ws + 2359296 + (size_t)SPLIT * 786432);  // SPLIT*16*192 f32

  proj_kernel<<<480, 256, 0, stream>>>(x0, x1, x2, qw, qb, kw, kb, vw, vb,
                                       Q0h, K1h, V1f, K2b, V2b);
  attn_kernel<<<SPLIT * 192, 256, 0, stream>>>(Q0h, K1h, V1f, K2b, V2b,
                                               Op, lp);
  outproj_kernel<<<192, 256, 0, stream>>>(Op, lp, cw, cb, out);
}

// Round 12
// 155.176 us; speedup vs baseline: 1.1596x; 1.0239x over previous
//
#include <hip/hip_runtime.h>

typedef float f4v __attribute__((ext_vector_type(4)));
typedef _Float16 h2v __attribute__((ext_vector_type(2)));
typedef _Float16 h4v __attribute__((ext_vector_type(4)));
typedef _Float16 h8v __attribute__((ext_vector_type(8)));
typedef __fp16 g4 __attribute__((ext_vector_type(4)));
typedef __fp16 g8 __attribute__((ext_vector_type(8)));
typedef unsigned short u16;
typedef unsigned int u32;

// B=2, T=192, C=512, H=8, HS=64, ORDER=3; scale = 1/sqrt(64) = 0.125
#define SPLIT 8
#define ESC 0.18033688011112042f  // 0.125 * log2(e), folded into Q at proj

__device__ __forceinline__ h2v pkh(float lo, float hi) {
  return __builtin_bit_cast(h2v, __builtin_amdgcn_cvt_pkrtz(lo, hi));
}
__device__ __forceinline__ f4v mfma_k32(h8v a, h8v b, f4v c) {
  return __builtin_amdgcn_mfma_f32_16x16x32_f16(
      __builtin_bit_cast(g8, a), __builtin_bit_cast(g8, b), c, 0, 0, 0);
}
__device__ __forceinline__ f4v mfma_k16(h4v a, h4v b, f4v c) {
  return __builtin_amdgcn_mfma_f32_16x16x16f16(
      __builtin_bit_cast(g4, a), __builtin_bit_cast(g4, b), c, 0, 0, 0);
}

// ---------------- projection kernel ----------------
// grid = 5 slots * 16 bh * 6 t-tiles = 480 blocks, 256 threads.
// Tile 32(t) x 64(d), K=512, register-dbuf staging.
// Outputs: Q0h/K1h/K2b/V2b as f16 (Q pre-scaled by ESC), V1f as f32
// (V1 multiplies outside MFMA -> keep full precision there).
__global__ __launch_bounds__(256) void proj_kernel(
    const float* __restrict__ x0, const float* __restrict__ x1,
    const float* __restrict__ x2,
    const float* __restrict__ qw, const float* __restrict__ qb,
    const float* __restrict__ kw, const float* __restrict__ kb,
    const float* __restrict__ vw, const float* __restrict__ vb,
    u16* __restrict__ Q0h, u16* __restrict__ K1h, float* __restrict__ V1f,
    u16* __restrict__ K2b, u16* __restrict__ V2b) {
  __shared__ float xs[32][36];   // [c][m]
  __shared__ float wsh[32][68];  // [c][n]

  int bx = blockIdx.x;
  int slot = bx / 96;
  int rem = bx - slot * 96;
  int bh = rem / 6;
  int tt = rem - bh * 6;
  int b = bh >> 3, h = bh & 7;
  int t0 = tt * 32;

  const float* x; const float* w; const float* bias; int o;
  float* outf = nullptr; u16* outb = nullptr;
  switch (slot) {
    case 0: x = x0; w = qw; bias = qb; o = 0; outb = Q0h; break;
    case 1: x = x1; w = kw; bias = kb; o = 1; outb = K1h; break;
    case 2: x = x2; w = kw; bias = kb; o = 2; outb = K2b; break;
    case 3: x = x1; w = vw; bias = vb; o = 1; outf = V1f; break;
    default: x = x2; w = vw; bias = vb; o = 2; outb = V2b; break;
  }
  x += b * 192 * 512;
  w += (h * 3 + o) * 64 * 512;
  bias += (h * 3 + o) * 64;

  int tid = threadIdx.x;
  int m2 = tid >> 4, nq = tid & 15;
  int mA = tid >> 3, clA = (tid & 7) * 4;      // A-stage coords
  int nB0 = tid >> 3, nB1 = (256 + tid) >> 3;  // B-stage coords (2 rows)
  float acc[2][4] = {};

  float4 pX, pW0, pW1;  // prefetch registers
  pX = *(const float4*)(x + (t0 + mA) * 512 + clA);
  pW0 = *(const float4*)(w + nB0 * 512 + clA);
  pW1 = *(const float4*)(w + nB1 * 512 + clA);

  for (int kc = 0; kc < 16; ++kc) {
    xs[clA][mA] = pX.x; xs[clA + 1][mA] = pX.y;
    xs[clA + 2][mA] = pX.z; xs[clA + 3][mA] = pX.w;
    wsh[clA][nB0] = pW0.x; wsh[clA + 1][nB0] = pW0.y;
    wsh[clA + 2][nB0] = pW0.z; wsh[clA + 3][nB0] = pW0.w;
    wsh[clA][nB1] = pW1.x; wsh[clA + 1][nB1] = pW1.y;
    wsh[clA + 2][nB1] = pW1.z; wsh[clA + 3][nB1] = pW1.w;
    __syncthreads();
    if (kc < 15) {  // prefetch next tile; latency hidden by compute below
      int cb0 = (kc + 1) * 32;
      pX = *(const float4*)(x + (t0 + mA) * 512 + cb0 + clA);
      pW0 = *(const float4*)(w + nB0 * 512 + cb0 + clA);
      pW1 = *(const float4*)(w + nB1 * 512 + cb0 + clA);
    }
#pragma unroll
    for (int c = 0; c < 32; ++c) {
      float2 av = *(const float2*)&xs[c][m2 * 2];
      float4 bv = *(const float4*)&wsh[c][nq * 4];
      acc[0][0] += av.x * bv.x; acc[0][1] += av.x * bv.y;
      acc[0][2] += av.x * bv.z; acc[0][3] += av.x * bv.w;
      acc[1][0] += av.y * bv.x; acc[1][1] += av.y * bv.y;
      acc[1][2] += av.y * bv.z; acc[1][3] += av.y * bv.w;
    }
    __syncthreads();
  }

  float4 bias4 = *(const float4*)(bias + nq * 4);
#pragma unroll
  for (int i = 0; i < 2; ++i) {
    int t = t0 + m2 * 2 + i;
    long base = ((long)(bh * 192 + t)) * 64 + nq * 4;
    float o0 = acc[i][0] + bias4.x;
    float o1 = acc[i][1] + bias4.y;
    float o2 = acc[i][2] + bias4.z;
    float o3 = acc[i][3] + bias4.w;
    if (slot == 0) {  // fold attention scale+log2e into Q
      o0 *= ESC; o1 *= ESC; o2 *= ESC; o3 *= ESC;
    }
    if (outf) {
      float4 st = {o0, o1, o2, o3};
      *(float4*)(outf + base) = st;
    } else {
      h2v a = pkh(o0, o1), c2 = pkh(o2, o3);
      uint2 st = {__builtin_bit_cast(u32, a), __builtin_bit_cast(u32, c2)};
      *(uint2*)(outb + base) = st;
    }
  }
}

// ---------------- attention kernel ----------------
// grid = SPLIT*16*12 = 1536 blocks, 256 threads (4 waves), LDS = 25856 B.
//
// Operand-swapped scores: S^T = mfma(A=K2, B=Q*K1) puts the output with
// i in lane&15 and k in (quad, reg) -- which is EXACTLY the A-fragment
// layout for the PV matmul.  So P = exp2(S) never touches LDS: convert
// in-register with cvt_pkrtz and feed the PV mfma directly.  No barriers
// in the main loop; waves are independent (each owns a 48-k slice, all d).
// BISECT NOTE: round-11 PASSING source with two verified-safe changes:
// (a) SPLIT 4 -> 8 (grouping identical to the r6 PASS, bit-identical
//     absmax both times);
// (b) LDS phase-reuse: V2T (25856 B) is dead after the v2g fragment
//     reads, so K1/V1 are staged to REGISTERS early (loads overlap V2T
//     staging) and written into the recycled V2T region after a barrier.
// LDS 44288 -> 25856 B => 6 blocks/CU, grid 1536 = 6/CU: occupancy
// 12 -> 24 waves/CU to cover the serial per-j chain (r11: VALU 54%,
// occupancy 20% -- latency-bound on 3 waves/SIMD).
// Loop body byte-identical (single S/P chain; ILP-doubling variants
// miscompile -- rounds 3/4/7/8) -> bit-exact output.
__global__ __launch_bounds__(256, 4) void attn_kernel(
    const u16* __restrict__ Q0h, const u16* __restrict__ K1h,
    const float* __restrict__ V1f, const u16* __restrict__ K2b,
    const u16* __restrict__ V2b, float* __restrict__ Op,
    float* __restrict__ lp) {
  __shared__ __align__(16) char smem[25856];
  int bx = blockIdx.x;
  int sp = bx / 192;
  int rem = bx - sp * 192;
  int bh = rem / 12;
  int itile = rem - bh * 12;
  int i0 = itile * 16;
  int js = sp * 24;
  int tid = threadIdx.x;
  int wave = tid >> 6;
  int lane = tid & 63;
  int l15 = lane & 15;
  int quad = lane >> 4;

  // K1s/V1s live in the recycled V2T region after the v2g reads.
  u16* K1s = (u16*)smem;                // [24 j][64 d] u16 f16, 3072 B
  float* V1s = (float*)(smem + 3072);   // [24 j][64 d] f32, 6144 B

  // ---- early register staging of K1/V1 (latency overlaps V2T stage)
  u32 kreg0, kreg1, kreg2;
  float2 vreg0, vreg1, vreg2;
  {
    const u32* ksrc = (const u32*)(K1h + (bh * 192 + js) * 64);  // 768 u32
    kreg0 = ksrc[tid]; kreg1 = ksrc[256 + tid]; kreg2 = ksrc[512 + tid];
    const float2* vsrc2 = (const float2*)(V1f + (bh * 192 + js) * 64);
    vreg0 = vsrc2[tid]; vreg1 = vsrc2[256 + tid]; vreg2 = vsrc2[512 + tid];
  }

  // ---- prologue: stage V2^T [64 d][202 pad] u16 (natural k order)
  u16* V2T = (u16*)smem;
  {
    const u32* vsrc = (const u32*)V2b + bh * 6144;
#pragma unroll
    for (int r = 0; r < 24; ++r) {
      int idx = r * 256 + tid;
      int k = idx >> 5, d2 = idx & 31;
      u32 v = vsrc[idx];
      V2T[(d2 * 2) * 202 + k] = (u16)v;
      V2T[(d2 * 2 + 1) * 202 + k] = (u16)(v >> 16);
    }
  }
  // K2 A-fragments straight from global (rows k = w*48+nt*16+l15, kdim d)
  h8v k2f[3][2];
#pragma unroll
  for (int nt = 0; nt < 3; ++nt)
#pragma unroll
    for (int ks = 0; ks < 2; ++ks)
      k2f[nt][ks] = *(const h8v*)(K2b +
          (bh * 192 + wave * 48 + nt * 16 + l15) * 64 + ks * 32 + quad * 8);
  // Q B-fragments (kdim d = quad*8+idx (+32), col i = l15), pre-scaled ESC
  const u16* qq = Q0h + (bh * 192 + i0 + l15) * 64 + quad * 8;
  h8v qh0 = *(const h8v*)qq;
  h8v qh1 = *(const h8v*)(qq + 32);
  __syncthreads();
  // V2 B-frags for PV: grp0 k = w48+{quad*4+0..3, 16+quad*4+0..3},
  // grp1 k = w48+32+quad*4+0..3; col d = dt*16+l15.  u32 reads (stride
  // 404 B is only 4B-aligned for odd d).
  h8v v2g0[4]; h4v v2g1[4];
#pragma unroll
  for (int dt = 0; dt < 4; ++dt) {
    const char* p = smem + (dt * 16 + l15) * 404 + wave * 96 + quad * 8;
    union { h8v v; u32 w[4]; } u0;
    u0.w[0] = *(const u32*)p;        u0.w[1] = *(const u32*)(p + 4);
    u0.w[2] = *(const u32*)(p + 32); u0.w[3] = *(const u32*)(p + 36);
    v2g0[dt] = u0.v;
    union { h4v v; u32 w[2]; } u1;
    u1.w[0] = *(const u32*)(p + 64); u1.w[1] = *(const u32*)(p + 68);
    v2g1[dt] = u1.v;
  }
  __syncthreads();  // v2g in regs; V2T region now dead -> recycle
  // write K1/V1 from staging registers into the recycled region
  ((u32*)K1s)[tid] = kreg0;
  ((u32*)K1s)[256 + tid] = kreg1;
  ((u32*)K1s)[512 + tid] = kreg2;
  ((float2*)V1s)[tid] = vreg0;
  ((float2*)V1s)[256 + tid] = vreg1;
  ((float2*)V1s)[512 + tid] = vreg2;
  __syncthreads();  // K1s/V1s staged

  f4v Oacc[4] = {};
  float lsum = 0.f;
  const f4v z = {0.f, 0.f, 0.f, 0.f};

#pragma unroll 1
  for (int j = 0; j < 24; ++j) {
    // B-frag of S^T: Q~[i,d]*K1[j,d] via packed f16 mul (K1 from LDS)
    h8v c0 = *(const h8v*)(K1s + j * 64 + quad * 8);
    h8v c1 = *(const h8v*)(K1s + j * 64 + 32 + quad * 8);
    h8v B0 = qh0 * c0, B1 = qh1 * c1;
    // S^T[k=w48+nt*16+quad*4+r][i=l15], sum over d=0..63
    f4v s0 = mfma_k32(k2f[0][0], B0, z);
    f4v s1 = mfma_k32(k2f[1][0], B0, z);
    f4v s2 = mfma_k32(k2f[2][0], B0, z);
    s0 = mfma_k32(k2f[0][1], B1, s0);
    s1 = mfma_k32(k2f[1][1], B1, s1);
    s2 = mfma_k32(k2f[2][1], B1, s2);
    float p[12];
#pragma unroll
    for (int r = 0; r < 4; ++r) {
      p[r] = __builtin_amdgcn_exp2f(s0[r]);
      p[4 + r] = __builtin_amdgcn_exp2f(s1[r]);
      p[8 + r] = __builtin_amdgcn_exp2f(s2[r]);
    }
    lsum += (((p[0] + p[1]) + (p[2] + p[3])) + ((p[4] + p[5]) + (p[6] + p[7]))) +
            ((p[8] + p[9]) + (p[10] + p[11]));
    // P already in A-fragment layout: row i=l15, k in (quad, idx)
    union { h8v v; h2v h[4]; } pa0;
    pa0.h[0] = pkh(p[0], p[1]);  pa0.h[1] = pkh(p[2], p[3]);
    pa0.h[2] = pkh(p[4], p[5]);  pa0.h[3] = pkh(p[6], p[7]);
    union { h4v v; h2v h[2]; } pa1;
    pa1.h[0] = pkh(p[8], p[9]);  pa1.h[1] = pkh(p[10], p[11]);
    float v1r0 = V1s[j * 64 + l15];
    float v1r1 = V1s[j * 64 + 16 + l15];
    float v1r2 = V1s[j * 64 + 32 + l15];
    float v1r3 = V1s[j * 64 + 48 + l15];
    // W_j[i,d] over this wave's 48 k, then O += V1[j,d]*W_j
#pragma unroll
    for (int dt = 0; dt < 4; ++dt) {
      f4v w = mfma_k32(pa0.v, v2g0[dt], z);
      w = mfma_k16(pa1.v, v2g1[dt], w);
      float v1x = dt == 0 ? v1r0 : dt == 1 ? v1r1 : dt == 2 ? v1r2 : v1r3;
      Oacc[dt][0] = fmaf(v1x, w[0], Oacc[dt][0]);
      Oacc[dt][1] = fmaf(v1x, w[1], Oacc[dt][1]);
      Oacc[dt][2] = fmaf(v1x, w[2], Oacc[dt][2]);
      Oacc[dt][3] = fmaf(v1x, w[3], Oacc[dt][3]);
    }
  }

  // ---- epilogue: cross-wave k-slice reduction of O and l
  __syncthreads();  // all waves done; smem free
  float* ored = (float*)smem;            // 4 waves x [16 i][64 d] f32
  float* lred = (float*)(smem + 16384);  // 64 f32
  float* ow = ored + wave * 1024;
#pragma unroll
  for (int dt = 0; dt < 4; ++dt)
#pragma unroll
    for (int r = 0; r < 4; ++r)
      ow[(quad * 4 + r) * 64 + dt * 16 + l15] = Oacc[dt][r];
  lsum += __shfl_xor(lsum, 16);
  lsum += __shfl_xor(lsum, 32);
  if (quad == 0) lred[wave * 16 + l15] = lsum;
  __syncthreads();
  f4v s = *(const f4v*)(ored + tid * 4);
  s += *(const f4v*)(ored + 1024 + tid * 4);
  s += *(const f4v*)(ored + 2048 + tid * 4);
  s += *(const f4v*)(ored + 3072 + tid * 4);
  *(f4v*)(Op + ((long)(sp * 16 + bh) * 192 + i0) * 64 + tid * 4) = s;
  if (tid < 16)
    lp[(sp * 16 + bh) * 192 + i0 + tid] =
        lred[tid] + lred[16 + tid] + lred[32 + tid] + lred[48 + tid];
}

// ---------------- output projection (split-combine + 1/l fused) ----------
// grid = 24 mt(16) * 8 nt(64) = 192 blocks, register-dbuf staging.
__global__ __launch_bounds__(256) void outproj_kernel(
    const float* __restrict__ Op, const float* __restrict__ lp,
    const float* __restrict__ cw, const float* __restrict__ cb,
    float* __restrict__ out) {
  __shared__ float xs[32][20];   // [c][m]
  __shared__ float wsh[32][68];  // [c][n]
  __shared__ float linv[8][16];  // [h][m]
  int bx = blockIdx.x;
  int mt = bx >> 3, nt = bx & 7;
  int m0 = mt * 16;
  int b = m0 / 192;
  int t0 = m0 - b * 192;
  int n0 = nt * 64;
  int tid = threadIdx.x;

  if (tid < 128) {
    int h = tid >> 4, ml = tid & 15;
    float s = 0.f;
#pragma unroll
    for (int sp = 0; sp < SPLIT; ++sp)
      s += lp[(sp * 16 + b * 8 + h) * 192 + t0 + ml];
    linv[h][ml] = 1.0f / s;
  }

  int mA = tid >> 3, clA = (tid & 7) * 4;  // A-stage (tid<128 only)
  int nB0 = tid >> 3, nB1 = (256 + tid) >> 3;
  int m = tid >> 4, nq = tid & 15;
  float acc[4] = {};

  float4 pA[SPLIT];
  float4 pW0, pW1;
  {  // prefetch kc = 0 (h=0, d0=0)
    if (tid < 128) {
#pragma unroll
      for (int sp = 0; sp < SPLIT; ++sp)
        pA[sp] = *(const float4*)(
            Op + (long)((sp * 16 + b * 8) * 192 + t0 + mA) * 64 + clA);
    }
    pW0 = *(const float4*)(cw + (long)(n0 + nB0) * 512 + clA);
    pW1 = *(const float4*)(cw + (long)(n0 + nB1) * 512 + clA);
  }
  __syncthreads();  // linv ready

  for (int kc = 0; kc < 16; ++kc) {
    int h = kc >> 1;
    if (tid < 128) {  // combine SPLIT partials, scale 1/l, store [c][m]
      float4 s = pA[0];
#pragma unroll
      for (int sp = 1; sp < SPLIT; ++sp) {
        s.x += pA[sp].x; s.y += pA[sp].y; s.z += pA[sp].z; s.w += pA[sp].w;
      }
      float li = linv[h][mA];
      xs[clA][mA] = s.x * li; xs[clA + 1][mA] = s.y * li;
      xs[clA + 2][mA] = s.z * li; xs[clA + 3][mA] = s.w * li;
    }
    wsh[clA][nB0] = pW0.x; wsh[clA + 1][nB0] = pW0.y;
    wsh[clA + 2][nB0] = pW0.z; wsh[clA + 3][nB0] = pW0.w;
    wsh[clA][nB1] = pW1.x; wsh[clA + 1][nB1] = pW1.y;
    wsh[clA + 2][nB1] = pW1.z; wsh[clA + 3][nB1] = pW1.w;
    __syncthreads();
    if (kc < 15) {  // prefetch next kc during compute
      int h2 = (kc + 1) >> 1, d2 = ((kc + 1) & 1) * 32;
      if (tid < 128) {
#pragma unroll
        for (int sp = 0; sp < SPLIT; ++sp)
          pA[sp] = *(const float4*)(
              Op + (long)((sp * 16 + b * 8 + h2) * 192 + t0 + mA) * 64 + d2 +
              clA);
      }
      pW0 = *(const float4*)(cw + (long)(n0 + nB0) * 512 + h2 * 64 + d2 + clA);
      pW1 = *(const float4*)(cw + (long)(n0 + nB1) * 512 + h2 * 64 + d2 + clA);
    }
#pragma unroll
    for (int c = 0; c < 32; ++c) {
      float a = xs[c][m];
      float4 bv = *(const float4*)&wsh[c][nq * 4];
      acc[0] += a * bv.x; acc[1] += a * bv.y;
      acc[2] += a * bv.z; acc[3] += a * bv.w;
    }
    __syncthreads();
  }

  float4 bias = *(const float4*)(cb + n0 + nq * 4);
  float4 st;
  st.x = acc[0] + bias.x;
  st.y = acc[1] + bias.y;
  st.z = acc[2] + bias.z;
  st.w = acc[3] + bias.w;
  *(float4*)(out + (long)(b * 192 + t0 + m) * 512 + n0 + nq * 4) = st;
}

extern "C" void kernel_launch(void* const* d_in, const int* in_sizes, int n_in,
                              void* d_out, int out_size, void* d_ws, size_t ws_size,
                              hipStream_t stream) {
  const float* x0 = (const float*)d_in[0];
  const float* x1 = (const float*)d_in[1];
  const float* x2 = (const float*)d_in[2];
  const float* qw = (const float*)d_in[3];
  const float* qb = (const float*)d_in[4];
  const float* kw = (const float*)d_in[5];
  const float* kb = (const float*)d_in[6];
  const float* vb2 = (const float*)d_in[8];
  const float* vw = (const float*)d_in[7];
  const float* cw = (const float*)d_in[9];
  const float* cb = (const float*)d_in[10];
  float* out = (float*)d_out;

  // workspace carve
  char* ws = (char*)d_ws;
  u16* Q0h = (u16*)(ws + 0);            // 16*192*64 f16 (pre-scaled by ESC)
  u16* K1h = (u16*)(ws + 393216);       // 16*192*64 f16
  float* V1f = (float*)(ws + 786432);   // 16*192*64 f32
  u16* K2b = (u16*)(ws + 1572864);      // 16*192*64 f16
  u16* V2b = (u16*)(ws + 1966080);      // 16*192*64 f16
  float* Op = (float*)(ws + 2359296);   // SPLIT*16*192*64 f32 = 6291456 B
  float* lp = (float*)(ws + 2359296 + (size_t)SPLIT * 786432);  // SPLIT*16*192 f32

  proj_kernel<<<480, 256, 0, stream>>>(x0, x1, x2, qw, qb, kw, kb, vw, vb2,
                                       Q0h, K1h, V1f, K2b, V2b);
  attn_kernel<<<SPLIT * 192, 256, 0, stream>>>(Q0h, K1h, V1f, K2b, V2b,
                                               Op, lp);
  outproj_kernel<<<192, 256, 0, stream>>>(Op, lp, cw, cb, out);
}